// Round 4
// baseline (474.225 us; speedup 1.0000x reference)
//
#include <hip/hip_runtime.h>
#include <math.h>

#define L_TOT 2304
#define C_TOT 128
#define NBLK 576

typedef float v4f  __attribute__((ext_vector_type(4)));
typedef __bf16 v8bf __attribute__((ext_vector_type(8)));
typedef __bf16 v4bf __attribute__((ext_vector_type(4)));

#define MFMA_16x16x32_BF16(A, B, C) __builtin_amdgcn_mfma_f32_16x16x32_bf16((A), (B), (C), 0, 0, 0)

struct MegaP {
  const float *freq, *spat;
  const float *Wq, *bq, *Wk, *bk, *Wv, *bv, *Wo, *bo;
  float *SF; float *Qb; float *AO;
  __bf16 *K16; __bf16 *V16;
  float *out;
  int *bar;   // 6 ints, zeroed each launch: (cnt,flag) x3
};

// Device-scope grid barrier. Safe because all 576 blocks are co-resident
// (LDS 47360B -> 3 blk/CU, launch_bounds(256,3) caps VGPR; capacity 768 >= 576).
// Release on cnt (ACQ_REL add), release store on flag, acquire spin -> all
// prior writes of all blocks visible after return (XCD-coherent, G16).
__device__ __forceinline__ void gbar(int* cnt, int* flag){
  __syncthreads();
  if (threadIdx.x == 0){
    __threadfence();
    int old = __hip_atomic_fetch_add(cnt, 1, __ATOMIC_ACQ_REL, __HIP_MEMORY_SCOPE_AGENT);
    if (old == NBLK - 1){
      __hip_atomic_store(flag, 1, __ATOMIC_RELEASE, __HIP_MEMORY_SCOPE_AGENT);
    } else {
      while (!__hip_atomic_load(flag, __ATOMIC_ACQUIRE, __HIP_MEMORY_SCOPE_AGENT))
        __builtin_amdgcn_s_sleep(2);
    }
  }
  __syncthreads();
}

__global__ __launch_bounds__(256, 3) void k_mega(MegaP p){
  __shared__ __align__(16) unsigned char smraw[47360];
  const int tid = threadIdx.x;
  const int blk = blockIdx.x;

  // ================= P0: 2D DCT, blocks 0..255 (one (b,c) image each) =================
  if (blk < 256){
    float* Ds  = (float*)smraw;   // D[k][n]
    float* DTs = Ds + 2304;       // D^T[n][k]
    float* Xs  = Ds + 4608;
    float* Ts  = Ds + 6912;       // total 36864 B
    const float* Xi = p.spat + (size_t)blk * 2304;
    float* Fi = p.SF + (size_t)blk * 2304;
    for (int i = tid; i < 2304; i += 256){
      int k = i / 48, n = i - k * 48;
      int m = ((2 * n + 1) * k) % 192;
      float v = cosf(0.032724923474893679f * (float)m) * 0.204124145231931508f;
      if (k == 0) v *= 0.707106781186547524f;
      Ds[k * 48 + n] = v;
      DTs[n * 48 + k] = v;
      Xs[i] = Xi[i];
    }
    __syncthreads();
    int tr = (tid >> 4) * 3, tc = (tid & 15) * 3;
    {
      float a[3][3] = {};
      for (int n = 0; n < 48; n++){
        float x0 = Xs[tr * 48 + n], x1 = Xs[(tr + 1) * 48 + n], x2 = Xs[(tr + 2) * 48 + n];
        float d0 = DTs[n * 48 + tc], d1 = DTs[n * 48 + tc + 1], d2 = DTs[n * 48 + tc + 2];
        a[0][0] += x0 * d0; a[0][1] += x0 * d1; a[0][2] += x0 * d2;
        a[1][0] += x1 * d0; a[1][1] += x1 * d1; a[1][2] += x1 * d2;
        a[2][0] += x2 * d0; a[2][1] += x2 * d1; a[2][2] += x2 * d2;
      }
      #pragma unroll
      for (int i = 0; i < 3; i++)
        #pragma unroll
        for (int j = 0; j < 3; j++)
          Ts[(tr + i) * 48 + tc + j] = a[i][j];
    }
    __syncthreads();
    {
      float c[3][3] = {};
      for (int m = 0; m < 48; m++){
        float d0 = Ds[tr * 48 + m], d1 = Ds[(tr + 1) * 48 + m], d2 = Ds[(tr + 2) * 48 + m];
        float t0 = Ts[m * 48 + tc], t1 = Ts[m * 48 + tc + 1], t2 = Ts[m * 48 + tc + 2];
        c[0][0] += d0 * t0; c[0][1] += d0 * t1; c[0][2] += d0 * t2;
        c[1][0] += d1 * t0; c[1][1] += d1 * t1; c[1][2] += d1 * t2;
        c[2][0] += d2 * t0; c[2][1] += d2 * t1; c[2][2] += d2 * t2;
      }
      #pragma unroll
      for (int i = 0; i < 3; i++)
        #pragma unroll
        for (int j = 0; j < 3; j++)
          Fi[(tr + i) * 48 + tc + j] = c[i][j];
    }
  }
  gbar(p.bar + 0, p.bar + 1);

  // ================= P1: QKV projections, blocks 0..431 =================
  if (blk < 432){
    int x = blk % 36;
    int r = blk / 36;            // 0..11
    int y = r % 6, b = r / 6;
    int proj = y >> 1;
    int m0 = (y & 1) * 64;
    int n0 = x * 64;
    const float* X    = (proj == 0) ? p.freq : p.SF;
    const float* W    = (proj == 0) ? p.Wq : (proj == 1 ? p.Wk : p.Wv);
    const float* bias = (proj == 0) ? p.bq : (proj == 1 ? p.bk : p.bv);
    const float* Xb = X + (size_t)b * C_TOT * L_TOT;
    float* As = (float*)smraw;   // [16][68] padded
    float* Bs = As + 1088;       // [16][64]
    int tx = tid & 15, ty = tid >> 4;
    float acc[4][4] = {};
    for (int k0 = 0; k0 < C_TOT; k0 += 16){
      __syncthreads();
      for (int i = tid; i < 1024; i += 256){
        int m = i >> 4, k = i & 15;   // k fast -> 64B global segments
        As[k * 68 + m] = W[(size_t)(m0 + m) * C_TOT + k0 + k];
      }
      for (int i = tid; i < 1024; i += 256){
        int n = i & 63, k = i >> 6;
        Bs[k * 64 + n] = Xb[(size_t)(k0 + k) * L_TOT + n0 + n];
      }
      __syncthreads();
      #pragma unroll
      for (int k = 0; k < 16; k++){
        float4 a   = *(const float4*)&As[k * 68 + ty * 4];
        float4 bv4 = *(const float4*)&Bs[k * 64 + tx * 4];
        float av[4] = {a.x, a.y, a.z, a.w};
        float bb[4] = {bv4.x, bv4.y, bv4.z, bv4.w};
        #pragma unroll
        for (int i2 = 0; i2 < 4; i2++)
          #pragma unroll
          for (int j2 = 0; j2 < 4; j2++)
            acc[i2][j2] += av[i2] * bb[j2];
      }
    }
    if (proj == 0){
      float* Yb = p.Qb + (size_t)b * C_TOT * L_TOT;
      #pragma unroll
      for (int i2 = 0; i2 < 4; i2++){
        int o = m0 + ty * 4 + i2;
        float bo = bias[o];
        float4 rr;
        rr.x = acc[i2][0] + bo; rr.y = acc[i2][1] + bo;
        rr.z = acc[i2][2] + bo; rr.w = acc[i2][3] + bo;
        *(float4*)&Yb[(size_t)o * L_TOT + n0 + tx * 4] = rr;
      }
    } else {
      __bf16* Yb = ((proj == 1) ? p.K16 : p.V16) + (size_t)b * C_TOT * L_TOT;
      #pragma unroll
      for (int i2 = 0; i2 < 4; i2++){
        int o = m0 + ty * 4 + i2;
        float bo = bias[o];
        v4bf rr;
        rr[0] = (__bf16)(acc[i2][0] + bo); rr[1] = (__bf16)(acc[i2][1] + bo);
        rr[2] = (__bf16)(acc[i2][2] + bo); rr[3] = (__bf16)(acc[i2][3] + bo);
        *(v4bf*)&Yb[(size_t)o * L_TOT + n0 + tx * 4] = rr;
      }
    }
  }
  gbar(p.bar + 2, p.bar + 3);

  // ================= P2: MFMA flash attention, all 576 blocks =================
  {
    const int L = L_TOT;
    int x = blk % 36;
    int bh = blk / 36;           // 0..15
    int b = bh >> 3, h = bh & 7;
    int c0 = h * 16;
    const float*  Qb = p.Qb  + ((size_t)b * C_TOT + c0) * L;
    const __bf16* Kb = p.K16 + ((size_t)b * C_TOT + c0) * L;
    const __bf16* Vb = p.V16 + ((size_t)b * C_TOT + c0) * L;
    int wave = tid >> 6, lane = tid & 63;
    int qd = lane >> 4, cn = lane & 15;
    int l0 = x * 64;

    __bf16* smem = (__bf16*)smraw;       // 23680 bf16 = 47360 B
    __bf16* Kt = smem;                   // [256][36]
    __bf16* Vs = smem + 9216;            // [16][264]
    __bf16* Pt = smem + 13440;           // [4][4][640]

    v8bf qf[4];
    #pragma unroll
    for (int t = 0; t < 4; t++){
      #pragma unroll
      for (int j = 0; j < 8; j++) qf[t][j] = (__bf16)0.0f;
    }
    if (qd < 2){
      #pragma unroll
      for (int t = 0; t < 4; t++)
        #pragma unroll
        for (int j = 0; j < 8; j++)
          qf[t][j] = (__bf16)(Qb[(size_t)(qd * 8 + j) * L + l0 + t * 16 + cn] * 0.25f);
    }

    v4f acc[4];
    float den[4] = {0.f, 0.f, 0.f, 0.f};
    #pragma unroll
    for (int t = 0; t < 4; t++) acc[t] = (v4f){0.f, 0.f, 0.f, 0.f};

    for (int ch = 0; ch < 9; ch++){
      int s0 = ch * 256;
      __syncthreads();
      {
        const __bf16* Kc = Kb + s0 + tid;
        __bf16 kv[16];
        #pragma unroll
        for (int d = 0; d < 16; d++) kv[d] = Kc[(size_t)d * L];
        #pragma unroll
        for (int dq = 0; dq < 4; dq++){
          v4bf w;
          w[0] = kv[dq*4]; w[1] = kv[dq*4+1]; w[2] = kv[dq*4+2]; w[3] = kv[dq*4+3];
          *(v4bf*)&Kt[tid * 36 + dq * 4] = w;
        }
        int dd = tid >> 4, og = tid & 15;
        const __bf16* Vc = Vb + (size_t)dd * L + s0 + og * 16;
        *(v8bf*)&Vs[dd * 264 + og * 16]     = *(const v8bf*)Vc;
        *(v8bf*)&Vs[dd * 264 + og * 16 + 8] = *(const v8bf*)(Vc + 8);
      }
      __syncthreads();

      #pragma unroll
      for (int par = 0; par < 2; par++){
        int sb = wave * 64 + par * 32;
        v8bf a0, a1;
        #pragma unroll
        for (int j = 0; j < 8; j++){ a0[j] = (__bf16)0.0f; a1[j] = (__bf16)0.0f; }
        if (qd < 2){
          const __bf16* r0 = &Kt[(sb + cn) * 36 + qd * 8];
          v4bf lo0 = *(const v4bf*)r0, hi0 = *(const v4bf*)(r0 + 4);
          a0 = __builtin_shufflevector(lo0, hi0, 0, 1, 2, 3, 4, 5, 6, 7);
          const __bf16* r1 = &Kt[(sb + 16 + cn) * 36 + qd * 8];
          v4bf lo1 = *(const v4bf*)r1, hi1 = *(const v4bf*)(r1 + 4);
          a1 = __builtin_shufflevector(lo1, hi1, 0, 1, 2, 3, 4, 5, 6, 7);
        }
        v8bf vf = *(const v8bf*)&Vs[cn * 264 + sb + qd * 8];
        #pragma unroll
        for (int t = 0; t < 4; t++){
          v4f z = {0.f, 0.f, 0.f, 0.f};
          v4f st0 = MFMA_16x16x32_BF16(a0, qf[t], z);
          v4f st1 = MFMA_16x16x32_BF16(a1, qf[t], z);
          float p0[4], p1[4];
          #pragma unroll
          for (int i = 0; i < 4; i++){
            p0[i] = __expf(st0[i]); den[t] += p0[i];
            p1[i] = __expf(st1[i]); den[t] += p1[i];
          }
          v4bf w0, w1;
          #pragma unroll
          for (int i = 0; i < 4; i++){ w0[i] = (__bf16)p0[i]; w1[i] = (__bf16)p1[i]; }
          __bf16* Ptw = Pt + (wave * 4 + t) * 640;
          *(v4bf*)&Ptw[cn * 40 + qd * 4]      = w0;
          *(v4bf*)&Ptw[cn * 40 + 16 + qd * 4] = w1;
          v8bf pf = *(const v8bf*)&Ptw[cn * 40 + qd * 8];
          acc[t] = MFMA_16x16x32_BF16(vf, pf, acc[t]);
        }
      }
    }

    __syncthreads();
    float* redA = (float*)smem;            // 16384 B
    float* redD = (float*)(smem + 9216);   // 4096 B
    #pragma unroll
    for (int t = 0; t < 4; t++){
      *(v4f*)&redA[((wave * 4 + t) * 64 + lane) * 4] = acc[t];
      redD[(wave * 4 + t) * 64 + lane] = den[t];
    }
    __syncthreads();
    {
      int t = wave;
      v4f a = (v4f){0.f, 0.f, 0.f, 0.f};
      float dn = 0.f;
      #pragma unroll
      for (int w2 = 0; w2 < 4; w2++){
        v4f xx = *(const v4f*)&redA[((w2 * 4 + t) * 64 + lane) * 4];
        a[0] += xx[0]; a[1] += xx[1]; a[2] += xx[2]; a[3] += xx[3];
        dn += redD[(w2 * 4 + t) * 64 + lane];
      }
      dn += __shfl_xor(dn, 16);
      dn += __shfl_xor(dn, 32);
      float inv = 1.0f / dn;
      float* Ao = p.AO + ((size_t)b * C_TOT + c0) * L;
      #pragma unroll
      for (int r2 = 0; r2 < 4; r2++)
        Ao[(size_t)(qd * 4 + r2) * L + l0 + t * 16 + cn] = a[r2] * inv;
    }
  }
  gbar(p.bar + 4, p.bar + 5);

  // ================= P3: output projection, blocks 0..143 =================
  if (blk < 144){
    int x = blk % 36;
    int r = blk / 36;            // 0..3
    int m0 = (r & 1) * 64;
    int b = r >> 1;
    int n0 = x * 64;
    const float* Xb = p.AO + (size_t)b * C_TOT * L_TOT;
    float* Yb = p.out + (size_t)b * C_TOT * L_TOT;
    float* As = (float*)smraw;
    float* Bs = As + 1088;
    int tx = tid & 15, ty = tid >> 4;
    float acc[4][4] = {};
    for (int k0 = 0; k0 < C_TOT; k0 += 16){
      __syncthreads();
      for (int i = tid; i < 1024; i += 256){
        int m = i >> 4, k = i & 15;
        As[k * 68 + m] = p.Wo[(size_t)(m0 + m) * C_TOT + k0 + k];
      }
      for (int i = tid; i < 1024; i += 256){
        int n = i & 63, k = i >> 6;
        Bs[k * 64 + n] = Xb[(size_t)(k0 + k) * L_TOT + n0 + n];
      }
      __syncthreads();
      #pragma unroll
      for (int k = 0; k < 16; k++){
        float4 a   = *(const float4*)&As[k * 68 + ty * 4];
        float4 bv4 = *(const float4*)&Bs[k * 64 + tx * 4];
        float av[4] = {a.x, a.y, a.z, a.w};
        float bb[4] = {bv4.x, bv4.y, bv4.z, bv4.w};
        #pragma unroll
        for (int i2 = 0; i2 < 4; i2++)
          #pragma unroll
          for (int j2 = 0; j2 < 4; j2++)
            acc[i2][j2] += av[i2] * bb[j2];
      }
    }
    #pragma unroll
    for (int i2 = 0; i2 < 4; i2++){
      int o = m0 + ty * 4 + i2;
      float bo = p.bo[o];
      float4 rr;
      rr.x = acc[i2][0] + bo; rr.y = acc[i2][1] + bo;
      rr.z = acc[i2][2] + bo; rr.w = acc[i2][3] + bo;
      *(float4*)&Yb[(size_t)o * L_TOT + n0 + tx * 4] = rr;
    }
  }
}

extern "C" void kernel_launch(void* const* d_in, const int* in_sizes, int n_in,
                              void* d_out, int out_size, void* d_ws, size_t ws_size,
                              hipStream_t stream){
  float* ws = (float*)d_ws;
  MegaP p;
  p.freq = (const float*)d_in[0];
  p.spat = (const float*)d_in[1];
  p.Wq = (const float*)d_in[2]; p.bq = (const float*)d_in[3];
  p.Wk = (const float*)d_in[4]; p.bk = (const float*)d_in[5];
  p.Wv = (const float*)d_in[6]; p.bv = (const float*)d_in[7];
  p.Wo = (const float*)d_in[8]; p.bo = (const float*)d_in[9];
  p.SF  = ws;                        // 589824 floats
  p.Qb  = ws + 589824;               // 589824
  p.AO  = ws + 1179648;              // 589824
  p.K16 = (__bf16*)(ws + 1769472);   // 589824 bf16
  p.V16 = (__bf16*)(ws + 2064384);   // 589824 bf16
  p.out = (float*)d_out;
  p.bar = (int*)(ws + 8000000);      // barrier state, far from data

  hipMemsetAsync(p.bar, 0, 32, stream);          // re-init barrier every launch
  k_mega<<<dim3(NBLK), dim3(256), 0, stream>>>(p);
}

// Round 5
// 218.772 us; speedup vs baseline: 2.1677x; 2.1677x over previous
//
#include <hip/hip_runtime.h>
#include <math.h>

#define L_TOT 2304
#define C_TOT 128
#define NBLK 576
#define GSZ 16
#define NGRP 36

typedef float v4f  __attribute__((ext_vector_type(4)));
typedef __bf16 v8bf __attribute__((ext_vector_type(8)));
typedef __bf16 v4bf __attribute__((ext_vector_type(4)));

#define MFMA_16x16x32_BF16(A, B, C) __builtin_amdgcn_mfma_f32_16x16x32_bf16((A), (B), (C), 0, 0, 0)

struct MegaP {
  const float *freq, *spat;
  const float *Wq, *bq, *Wk, *bk, *Wv, *bv, *Wo, *bo;
  float *SF; float *Qb; float *AO;
  __bf16 *K16; __bf16 *V16;
  float *out;
  int *bar;   // 3 barriers x 1280 ints, zeroed each launch
};

// Two-level grid barrier. Groups of 16 blocks arrive on private 128B lines
// (parallel contention), group-leaders arrive on a global line, last sets flag.
// Spin: RELAXED atomic loads (bypass L1, no invalidate storm) + s_sleep backoff;
// one ACQUIRE load after flip re-establishes the R4-proven acquire chain.
// All 576 blocks co-resident: LDS 47616B -> 3 blk/CU, capacity 768 >= 576.
__device__ __forceinline__ void gbar(int* base, int grp){
  __syncthreads();
  if (threadIdx.x == 0){
    int* gc   = base + grp * 32;
    int* cnt  = base + NGRP * 32;
    int* flag = base + NGRP * 32 + 32;
    __threadfence();
    int old = __hip_atomic_fetch_add(gc, 1, __ATOMIC_RELAXED, __HIP_MEMORY_SCOPE_AGENT);
    if (old == GSZ - 1){
      int o2 = __hip_atomic_fetch_add(cnt, 1, __ATOMIC_RELAXED, __HIP_MEMORY_SCOPE_AGENT);
      if (o2 == NGRP - 1)
        __hip_atomic_store(flag, 1, __ATOMIC_RELEASE, __HIP_MEMORY_SCOPE_AGENT);
    }
    while (__hip_atomic_load(flag, __ATOMIC_RELAXED, __HIP_MEMORY_SCOPE_AGENT) == 0)
      __builtin_amdgcn_s_sleep(8);
    (void)__hip_atomic_load(flag, __ATOMIC_ACQUIRE, __HIP_MEMORY_SCOPE_AGENT);
  }
  __syncthreads();
}

// 64x64 channel-mixing GEMM tile: Y[m0+..][n0+..] = W*X + bias. Yf!=null -> f32 out.
__device__ __forceinline__ void proj_gemm(const float* __restrict__ W,
                                          const float* __restrict__ bias,
                                          const float* __restrict__ Xb,
                                          float* Yf, __bf16* Yh,
                                          int m0, int n0, float* As, float* Bs, int tid){
  int tx = tid & 15, ty = tid >> 4;
  float acc[4][4] = {};
  for (int k0 = 0; k0 < C_TOT; k0 += 16){
    __syncthreads();
    for (int i = tid; i < 1024; i += 256){
      int m = i >> 4, k = i & 15;          // k fast -> 64B global segments
      As[k * 68 + m] = W[(size_t)(m0 + m) * C_TOT + k0 + k];
    }
    for (int i = tid; i < 1024; i += 256){
      int n = i & 63, k = i >> 6;
      Bs[k * 64 + n] = Xb[(size_t)(k0 + k) * L_TOT + n0 + n];
    }
    __syncthreads();
    #pragma unroll
    for (int k = 0; k < 16; k++){
      float4 a   = *(const float4*)&As[k * 68 + ty * 4];
      float4 bv4 = *(const float4*)&Bs[k * 64 + tx * 4];
      float av[4] = {a.x, a.y, a.z, a.w};
      float bb[4] = {bv4.x, bv4.y, bv4.z, bv4.w};
      #pragma unroll
      for (int i2 = 0; i2 < 4; i2++)
        #pragma unroll
        for (int j2 = 0; j2 < 4; j2++)
          acc[i2][j2] += av[i2] * bb[j2];
    }
  }
  if (Yf){
    #pragma unroll
    for (int i2 = 0; i2 < 4; i2++){
      int o = m0 + ty * 4 + i2;
      float bo = bias[o];
      float4 rr;
      rr.x = acc[i2][0] + bo; rr.y = acc[i2][1] + bo;
      rr.z = acc[i2][2] + bo; rr.w = acc[i2][3] + bo;
      *(float4*)&Yf[(size_t)o * L_TOT + n0 + tx * 4] = rr;
    }
  } else {
    #pragma unroll
    for (int i2 = 0; i2 < 4; i2++){
      int o = m0 + ty * 4 + i2;
      float bo = bias[o];
      v4bf rr;
      rr[0] = (__bf16)(acc[i2][0] + bo); rr[1] = (__bf16)(acc[i2][1] + bo);
      rr[2] = (__bf16)(acc[i2][2] + bo); rr[3] = (__bf16)(acc[i2][3] + bo);
      *(v4bf*)&Yh[(size_t)o * L_TOT + n0 + tx * 4] = rr;
    }
  }
}

__global__ __launch_bounds__(256, 3) void k_mega(MegaP p){
  __shared__ __align__(16) unsigned char smraw[47616];
  const int tid = threadIdx.x;
  const int blk = blockIdx.x;
  const int grp = blk >> 4;

  // ===== P0: DCT (blocks 0..255) || Q-projection (blocks 256..399) =====
  if (blk < 256){
    // LDS rows padded to 49 (17 mod 32) -> conflict-free strided column reads
    float* Ds  = (float*)smraw;      // D[k][n]   48x49
    float* DTs = Ds + 2352;          // D^T[n][k] 48x49
    float* Xs  = Ds + 4704;          // 48x49
    float* Ts  = Ds + 7056;          // 48x49  (total 37632 B)
    const float* Xi = p.spat + (size_t)blk * 2304;
    float* Fi = p.SF + (size_t)blk * 2304;
    for (int i = tid; i < 2304; i += 256){
      int k = i / 48, n = i - k * 48;
      int m = ((2 * n + 1) * k) % 192;
      float v = cosf(0.032724923474893679f * (float)m) * 0.204124145231931508f;
      if (k == 0) v *= 0.707106781186547524f;
      Ds[k * 49 + n] = v;
      DTs[n * 49 + k] = v;
      Xs[k * 49 + n] = Xi[i];
    }
    __syncthreads();
    int tr = (tid >> 4) * 3, tc = (tid & 15) * 3;
    {
      float a[3][3] = {};
      for (int n = 0; n < 48; n++){
        float x0 = Xs[tr * 49 + n], x1 = Xs[(tr + 1) * 49 + n], x2 = Xs[(tr + 2) * 49 + n];
        float d0 = DTs[n * 49 + tc], d1 = DTs[n * 49 + tc + 1], d2 = DTs[n * 49 + tc + 2];
        a[0][0] += x0 * d0; a[0][1] += x0 * d1; a[0][2] += x0 * d2;
        a[1][0] += x1 * d0; a[1][1] += x1 * d1; a[1][2] += x1 * d2;
        a[2][0] += x2 * d0; a[2][1] += x2 * d1; a[2][2] += x2 * d2;
      }
      #pragma unroll
      for (int i = 0; i < 3; i++)
        #pragma unroll
        for (int j = 0; j < 3; j++)
          Ts[(tr + i) * 49 + tc + j] = a[i][j];
    }
    __syncthreads();
    {
      float c[3][3] = {};
      for (int m = 0; m < 48; m++){
        float d0 = Ds[tr * 49 + m], d1 = Ds[(tr + 1) * 49 + m], d2 = Ds[(tr + 2) * 49 + m];
        float t0 = Ts[m * 49 + tc], t1 = Ts[m * 49 + tc + 1], t2 = Ts[m * 49 + tc + 2];
        c[0][0] += d0 * t0; c[0][1] += d0 * t1; c[0][2] += d0 * t2;
        c[1][0] += d1 * t0; c[1][1] += d1 * t1; c[1][2] += d1 * t2;
        c[2][0] += d2 * t0; c[2][1] += d2 * t1; c[2][2] += d2 * t2;
      }
      #pragma unroll
      for (int i = 0; i < 3; i++)
        #pragma unroll
        for (int j = 0; j < 3; j++)
          Fi[(tr + i) * 48 + tc + j] = c[i][j];
    }
  } else if (blk < 400){
    int idx = blk - 256;
    int x = idx % 36, rr = idx / 36;         // rr 0..3
    int m0 = (rr & 1) * 64, b = rr >> 1;
    float* As = (float*)smraw;
    float* Bs = As + 1088;
    proj_gemm(p.Wq, p.bq, p.freq + (size_t)b * C_TOT * L_TOT,
              p.Qb + (size_t)b * C_TOT * L_TOT, (__bf16*)0,
              m0, x * 64, As, Bs, tid);
  }
  gbar(p.bar, grp);

  // ===== P1: K,V projections (blocks 0..287) =====
  if (blk < 288){
    int x = blk % 36, r = blk / 36;          // r 0..7
    int pr = r & 1, m0 = ((r >> 1) & 1) * 64, b = r >> 2;
    float* As = (float*)smraw;
    float* Bs = As + 1088;
    proj_gemm(pr ? p.Wv : p.Wk, pr ? p.bv : p.bk,
              p.SF + (size_t)b * C_TOT * L_TOT,
              (float*)0,
              (pr ? p.V16 : p.K16) + (size_t)b * C_TOT * L_TOT,
              m0, x * 64, As, Bs, tid);
  }
  gbar(p.bar + 1280, grp);

  // ===== P2: MFMA flash attention (all 576 blocks) =====
  {
    const int L = L_TOT;
    int x = blk % 36;
    int bh = blk / 36;
    int b = bh >> 3, h = bh & 7;
    int c0 = h * 16;
    const float*  Qb = p.Qb  + ((size_t)b * C_TOT + c0) * L;
    const __bf16* Kb = p.K16 + ((size_t)b * C_TOT + c0) * L;
    const __bf16* Vb = p.V16 + ((size_t)b * C_TOT + c0) * L;
    int wave = tid >> 6, lane = tid & 63;
    int qd = lane >> 4, cn = lane & 15;
    int l0 = x * 64;

    __bf16* smem = (__bf16*)smraw;
    __bf16* Kt = smem;                   // [256][36]
    __bf16* Vs = smem + 9216;            // [16][264]
    __bf16* Pt = smem + 13440;           // [4][4][640]

    v8bf qf[4];
    #pragma unroll
    for (int t = 0; t < 4; t++){
      #pragma unroll
      for (int j = 0; j < 8; j++) qf[t][j] = (__bf16)0.0f;
    }
    if (qd < 2){
      #pragma unroll
      for (int t = 0; t < 4; t++)
        #pragma unroll
        for (int j = 0; j < 8; j++)
          qf[t][j] = (__bf16)(Qb[(size_t)(qd * 8 + j) * L + l0 + t * 16 + cn] * 0.25f);
    }

    v4f acc[4];
    float den[4] = {0.f, 0.f, 0.f, 0.f};
    #pragma unroll
    for (int t = 0; t < 4; t++) acc[t] = (v4f){0.f, 0.f, 0.f, 0.f};

    for (int ch = 0; ch < 9; ch++){
      int s0 = ch * 256;
      __syncthreads();
      {
        const __bf16* Kc = Kb + s0 + tid;
        __bf16 kv[16];
        #pragma unroll
        for (int d = 0; d < 16; d++) kv[d] = Kc[(size_t)d * L];
        #pragma unroll
        for (int dq = 0; dq < 4; dq++){
          v4bf w;
          w[0] = kv[dq*4]; w[1] = kv[dq*4+1]; w[2] = kv[dq*4+2]; w[3] = kv[dq*4+3];
          *(v4bf*)&Kt[tid * 36 + dq * 4] = w;
        }
        int dd = tid >> 4, og = tid & 15;
        const __bf16* Vc = Vb + (size_t)dd * L + s0 + og * 16;
        *(v8bf*)&Vs[dd * 264 + og * 16]     = *(const v8bf*)Vc;
        *(v8bf*)&Vs[dd * 264 + og * 16 + 8] = *(const v8bf*)(Vc + 8);
      }
      __syncthreads();

      #pragma unroll
      for (int par = 0; par < 2; par++){
        int sb = wave * 64 + par * 32;
        v8bf a0, a1;
        #pragma unroll
        for (int j = 0; j < 8; j++){ a0[j] = (__bf16)0.0f; a1[j] = (__bf16)0.0f; }
        if (qd < 2){
          const __bf16* r0 = &Kt[(sb + cn) * 36 + qd * 8];
          v4bf lo0 = *(const v4bf*)r0, hi0 = *(const v4bf*)(r0 + 4);
          a0 = __builtin_shufflevector(lo0, hi0, 0, 1, 2, 3, 4, 5, 6, 7);
          const __bf16* r1 = &Kt[(sb + 16 + cn) * 36 + qd * 8];
          v4bf lo1 = *(const v4bf*)r1, hi1 = *(const v4bf*)(r1 + 4);
          a1 = __builtin_shufflevector(lo1, hi1, 0, 1, 2, 3, 4, 5, 6, 7);
        }
        v8bf vf = *(const v8bf*)&Vs[cn * 264 + sb + qd * 8];
        #pragma unroll
        for (int t = 0; t < 4; t++){
          v4f z = {0.f, 0.f, 0.f, 0.f};
          v4f st0 = MFMA_16x16x32_BF16(a0, qf[t], z);
          v4f st1 = MFMA_16x16x32_BF16(a1, qf[t], z);
          float p0[4], p1[4];
          #pragma unroll
          for (int i = 0; i < 4; i++){
            p0[i] = __expf(st0[i]); den[t] += p0[i];
            p1[i] = __expf(st1[i]); den[t] += p1[i];
          }
          v4bf w0, w1;
          #pragma unroll
          for (int i = 0; i < 4; i++){ w0[i] = (__bf16)p0[i]; w1[i] = (__bf16)p1[i]; }
          __bf16* Ptw = Pt + (wave * 4 + t) * 640;
          *(v4bf*)&Ptw[cn * 40 + qd * 4]      = w0;
          *(v4bf*)&Ptw[cn * 40 + 16 + qd * 4] = w1;
          v8bf pf = *(const v8bf*)&Ptw[cn * 40 + qd * 8];
          acc[t] = MFMA_16x16x32_BF16(vf, pf, acc[t]);
        }
      }
    }

    __syncthreads();
    float* redA = (float*)smem;
    float* redD = (float*)(smem + 9216);
    #pragma unroll
    for (int t = 0; t < 4; t++){
      *(v4f*)&redA[((wave * 4 + t) * 64 + lane) * 4] = acc[t];
      redD[(wave * 4 + t) * 64 + lane] = den[t];
    }
    __syncthreads();
    {
      int t = wave;
      v4f a = (v4f){0.f, 0.f, 0.f, 0.f};
      float dn = 0.f;
      #pragma unroll
      for (int w2 = 0; w2 < 4; w2++){
        v4f xx = *(const v4f*)&redA[((w2 * 4 + t) * 64 + lane) * 4];
        a[0] += xx[0]; a[1] += xx[1]; a[2] += xx[2]; a[3] += xx[3];
        dn += redD[(w2 * 4 + t) * 64 + lane];
      }
      dn += __shfl_xor(dn, 16);
      dn += __shfl_xor(dn, 32);
      float inv = 1.0f / dn;
      float* Ao = p.AO + ((size_t)b * C_TOT + c0) * L;
      #pragma unroll
      for (int r2 = 0; r2 < 4; r2++)
        Ao[(size_t)(qd * 4 + r2) * L + l0 + t * 16 + cn] = a[r2] * inv;
    }
  }
  gbar(p.bar + 2560, grp);

  // ===== P3: output projection (blocks 0..143) =====
  if (blk < 144){
    int x = blk % 36, rr = blk / 36;
    int m0 = (rr & 1) * 64, b = rr >> 1;
    float* As = (float*)smraw;
    float* Bs = As + 1088;
    proj_gemm(p.Wo, p.bo, p.AO + (size_t)b * C_TOT * L_TOT,
              p.out + (size_t)b * C_TOT * L_TOT, (__bf16*)0,
              m0, x * 64, As, Bs, tid);
  }
}

extern "C" void kernel_launch(void* const* d_in, const int* in_sizes, int n_in,
                              void* d_out, int out_size, void* d_ws, size_t ws_size,
                              hipStream_t stream){
  float* ws = (float*)d_ws;
  MegaP p;
  p.freq = (const float*)d_in[0];
  p.spat = (const float*)d_in[1];
  p.Wq = (const float*)d_in[2]; p.bq = (const float*)d_in[3];
  p.Wk = (const float*)d_in[4]; p.bk = (const float*)d_in[5];
  p.Wv = (const float*)d_in[6]; p.bv = (const float*)d_in[7];
  p.Wo = (const float*)d_in[8]; p.bo = (const float*)d_in[9];
  p.SF  = ws;                        // 589824 floats
  p.Qb  = ws + 589824;
  p.AO  = ws + 1179648;
  p.K16 = (__bf16*)(ws + 1769472);
  p.V16 = (__bf16*)(ws + 2064384);
  p.out = (float*)d_out;
  p.bar = (int*)(ws + 8000000);      // 3 x 1280 ints, far from data

  hipMemsetAsync(p.bar, 0, 3 * 1280 * sizeof(int), stream);
  k_mega<<<dim3(NBLK), dim3(256), 0, stream>>>(p);
}

// Round 6
// 155.178 us; speedup vs baseline: 3.0560x; 1.4098x over previous
//
#include <hip/hip_runtime.h>
#include <math.h>

#define L_TOT 2304
#define C_TOT 128

typedef float v4f  __attribute__((ext_vector_type(4)));
typedef __bf16 v8bf __attribute__((ext_vector_type(8)));
typedef __bf16 v4bf __attribute__((ext_vector_type(4)));

#define MFMA_16x16x32_BF16(A, B, C) __builtin_amdgcn_mfma_f32_16x16x32_bf16((A), (B), (C), 0, 0, 0)

// async 16B/lane global->LDS: LDS dest is wave-uniform base + lane*16 (linear!)
__device__ __forceinline__ void async_cp16(const __bf16* g, __bf16* l){
  __builtin_amdgcn_global_load_lds((const __attribute__((address_space(1))) unsigned int*)g,
                                   (__attribute__((address_space(3))) unsigned int*)l,
                                   16, 0, 0);
}

// ---------------- 2D DCT: F = D * X * D^T per (b,c) image ----------------
__global__ __launch_bounds__(256) void k_dct2d(const float* __restrict__ X,
                                               float* __restrict__ F){
  __shared__ float Ds[2352];   // 48x49 padded rows
  __shared__ float DTs[2352];
  __shared__ float Xs[2352];
  __shared__ float Ts[2352];
  const float* Xi = X + (size_t)blockIdx.x * 2304;
  float* Fi = F + (size_t)blockIdx.x * 2304;
  int tid = threadIdx.x;
  for (int i = tid; i < 2304; i += 256){
    int k = i / 48, n = i - k * 48;
    int m = ((2 * n + 1) * k) % 192;
    float v = cosf(0.032724923474893679f * (float)m) * 0.204124145231931508f;
    if (k == 0) v *= 0.707106781186547524f;
    Ds[k * 49 + n] = v;
    DTs[n * 49 + k] = v;
    Xs[k * 49 + n] = Xi[i];
  }
  __syncthreads();
  int tr = (tid >> 4) * 3, tc = (tid & 15) * 3;
  {
    float a[3][3] = {};
    for (int n = 0; n < 48; n++){
      float x0 = Xs[tr * 49 + n], x1 = Xs[(tr + 1) * 49 + n], x2 = Xs[(tr + 2) * 49 + n];
      float d0 = DTs[n * 49 + tc], d1 = DTs[n * 49 + tc + 1], d2 = DTs[n * 49 + tc + 2];
      a[0][0] += x0 * d0; a[0][1] += x0 * d1; a[0][2] += x0 * d2;
      a[1][0] += x1 * d0; a[1][1] += x1 * d1; a[1][2] += x1 * d2;
      a[2][0] += x2 * d0; a[2][1] += x2 * d1; a[2][2] += x2 * d2;
    }
    #pragma unroll
    for (int i = 0; i < 3; i++)
      #pragma unroll
      for (int j = 0; j < 3; j++)
        Ts[(tr + i) * 49 + tc + j] = a[i][j];
  }
  __syncthreads();
  {
    float c[3][3] = {};
    for (int m = 0; m < 48; m++){
      float d0 = Ds[tr * 49 + m], d1 = Ds[(tr + 1) * 49 + m], d2 = Ds[(tr + 2) * 49 + m];
      float t0 = Ts[m * 49 + tc], t1 = Ts[m * 49 + tc + 1], t2 = Ts[m * 49 + tc + 2];
      c[0][0] += d0 * t0; c[0][1] += d0 * t1; c[0][2] += d0 * t2;
      c[1][0] += d1 * t0; c[1][1] += d1 * t1; c[1][2] += d1 * t2;
      c[2][0] += d2 * t0; c[2][1] += d2 * t1; c[2][2] += d2 * t2;
    }
    #pragma unroll
    for (int i = 0; i < 3; i++)
      #pragma unroll
      for (int j = 0; j < 3; j++)
        Fi[(tr + i) * 48 + tc + j] = c[i][j];
  }
}

// ---------------- fused QKV projection ----------------
// y: 0,1 -> Q fp32 [c][l] ; 2,3 -> K bf16 TRANSPOSED [l][c], pre-scaled 0.25 ; 4,5 -> V bf16 [c][l]
__global__ __launch_bounds__(256) void k_proj_qkv(
    const float* __restrict__ freq, const float* __restrict__ SF,
    const float* __restrict__ Wq, const float* __restrict__ bq,
    const float* __restrict__ Wk, const float* __restrict__ bk,
    const float* __restrict__ Wv, const float* __restrict__ bv,
    float* __restrict__ Qo, __bf16* __restrict__ KTo, __bf16* __restrict__ Vo){
  const int L = L_TOT, C = C_TOT;
  int proj = blockIdx.y >> 1;
  int m0 = (blockIdx.y & 1) * 64;
  int b = blockIdx.z;
  const float* X    = (proj == 0) ? freq : SF;
  const float* W    = (proj == 0) ? Wq : (proj == 1 ? Wk : Wv);
  const float* bias = (proj == 0) ? bq : (proj == 1 ? bk : bv);
  const float* Xb = X + (size_t)b * C * L;
  int n0 = blockIdx.x * 64;
  __shared__ __align__(16) float As[16][68];
  __shared__ __align__(16) float Bs[16][64];
  int tid = threadIdx.x;
  int tx = tid & 15, ty = tid >> 4;
  float acc[4][4] = {};
  for (int k0 = 0; k0 < C; k0 += 16){
    __syncthreads();
    for (int i = tid; i < 1024; i += 256){
      int m = i >> 4, k = i & 15;
      As[k][m] = W[(size_t)(m0 + m) * C + k0 + k];
    }
    for (int i = tid; i < 1024; i += 256){
      int n = i & 63, k = i >> 6;
      Bs[k][n] = Xb[(size_t)(k0 + k) * L + n0 + n];
    }
    __syncthreads();
    #pragma unroll
    for (int k = 0; k < 16; k++){
      float4 a   = *(const float4*)&As[k][ty * 4];
      float4 bv4 = *(const float4*)&Bs[k][tx * 4];
      float av[4] = {a.x, a.y, a.z, a.w};
      float bb[4] = {bv4.x, bv4.y, bv4.z, bv4.w};
      #pragma unroll
      for (int i2 = 0; i2 < 4; i2++)
        #pragma unroll
        for (int j2 = 0; j2 < 4; j2++)
          acc[i2][j2] += av[i2] * bb[j2];
    }
  }
  if (proj == 0){
    float* Yb = Qo + (size_t)b * C * L;
    #pragma unroll
    for (int i2 = 0; i2 < 4; i2++){
      int o = m0 + ty * 4 + i2;
      float bo = bias[o];
      float4 rr;
      rr.x = acc[i2][0] + bo; rr.y = acc[i2][1] + bo;
      rr.z = acc[i2][2] + bo; rr.w = acc[i2][3] + bo;
      *(float4*)&Yb[(size_t)o * L + n0 + tx * 4] = rr;
    }
  } else if (proj == 1){
    // transposed K: KT[l][c], value = 0.25*(Wx+b)
    __bf16* Yb = KTo + (size_t)b * L * C;
    float bo[4];
    #pragma unroll
    for (int i2 = 0; i2 < 4; i2++) bo[i2] = bias[m0 + ty * 4 + i2];
    #pragma unroll
    for (int j2 = 0; j2 < 4; j2++){
      int n = n0 + tx * 4 + j2;
      v4bf rr;
      #pragma unroll
      for (int i2 = 0; i2 < 4; i2++)
        rr[i2] = (__bf16)((acc[i2][j2] + bo[i2]) * 0.25f);
      *(v4bf*)&Yb[(size_t)n * C + m0 + ty * 4] = rr;
    }
  } else {
    __bf16* Yb = Vo + (size_t)b * C * L;
    #pragma unroll
    for (int i2 = 0; i2 < 4; i2++){
      int o = m0 + ty * 4 + i2;
      float bo = bias[o];
      v4bf rr;
      rr[0] = (__bf16)(acc[i2][0] + bo); rr[1] = (__bf16)(acc[i2][1] + bo);
      rr[2] = (__bf16)(acc[i2][2] + bo); rr[3] = (__bf16)(acc[i2][3] + bo);
      *(v4bf*)&Yb[(size_t)o * L + n0 + tx * 4] = rr;
    }
  }
}

// ---------------- fp32 projection (Wo epilogue) ----------------
__global__ __launch_bounds__(256) void k_proj(const float* __restrict__ W,
                                              const float* __restrict__ bias,
                                              const float* __restrict__ X,
                                              float* __restrict__ Y){
  const int L = L_TOT, C = C_TOT;
  int b = blockIdx.z;
  const float* Xb = X + (size_t)b * C * L;
  float* Yb = Y + (size_t)b * C * L;
  int n0 = blockIdx.x * 64, m0 = blockIdx.y * 64;
  __shared__ __align__(16) float As[16][68];
  __shared__ __align__(16) float Bs[16][64];
  int tid = threadIdx.x;
  int tx = tid & 15, ty = tid >> 4;
  float acc[4][4] = {};
  for (int k0 = 0; k0 < C; k0 += 16){
    __syncthreads();
    for (int i = tid; i < 1024; i += 256){
      int m = i >> 4, k = i & 15;
      As[k][m] = W[(size_t)(m0 + m) * C + k0 + k];
    }
    for (int i = tid; i < 1024; i += 256){
      int n = i & 63, k = i >> 6;
      Bs[k][n] = Xb[(size_t)(k0 + k) * L + n0 + n];
    }
    __syncthreads();
    #pragma unroll
    for (int k = 0; k < 16; k++){
      float4 a   = *(const float4*)&As[k][ty * 4];
      float4 bv4 = *(const float4*)&Bs[k][tx * 4];
      float av[4] = {a.x, a.y, a.z, a.w};
      float bb[4] = {bv4.x, bv4.y, bv4.z, bv4.w};
      #pragma unroll
      for (int i2 = 0; i2 < 4; i2++)
        #pragma unroll
        for (int j2 = 0; j2 < 4; j2++)
          acc[i2][j2] += av[i2] * bb[j2];
    }
  }
  #pragma unroll
  for (int i2 = 0; i2 < 4; i2++){
    int o = m0 + ty * 4 + i2;
    float bo = bias[o];
    float4 rr;
    rr.x = acc[i2][0] + bo; rr.y = acc[i2][1] + bo;
    rr.z = acc[i2][2] + bo; rr.w = acc[i2][3] + bo;
    *(float4*)&Yb[(size_t)o * L + n0 + tx * 4] = rr;
  }
}

// ---------------- MFMA flash attention, async-staged ----------------
// K global layout [l][c] (pre-scaled 0.25): chunk rows are 32B -> global_load_lds
// into linear Kt[s][16]. V [c][l]: global_load_lds rows with source-side XOR
// swizzle (slot ^ (d&7)) so vf b128 reads spread over banks (linear LDS required
// by the gather; a pad would break it). Wave w owns s-subrange, all 4 l-tiles;
// softmax-without-max sums merge linearly across waves at the end.
__global__ __launch_bounds__(256) void k_attn(const float* __restrict__ Q,
                                              const __bf16* __restrict__ KT,
                                              const __bf16* __restrict__ V,
                                              float* __restrict__ AO){
  const int L = L_TOT;
  int bh = blockIdx.y;
  int b = bh >> 3, h = bh & 7;
  int c0 = h * 16;
  const float*  Qb  = Q  + ((size_t)b * C_TOT + c0) * L;
  const __bf16* KTb = KT + (size_t)b * L * C_TOT;
  const __bf16* Vb  = V  + ((size_t)b * C_TOT + c0) * L;
  int tid = threadIdx.x;
  int wave = tid >> 6, lane = tid & 63;
  int qd = lane >> 4, cn = lane & 15;
  int l0 = blockIdx.x * 64;

  // Kt[512][16] (16KB) | Vs[16][512] (16KB) | Pt[4 waves][16*40] (5KB)
  __shared__ __align__(16) __bf16 smem[8192 + 8192 + 2560];
  __bf16* Kt  = smem;
  __bf16* Vs  = smem + 8192;
  __bf16* Ptw = smem + 16384 + wave * 640;

  // Q B-frags (k=d): quads 2,3 zero (d padded 16->32)
  v8bf qf[4];
  #pragma unroll
  for (int t = 0; t < 4; t++){
    #pragma unroll
    for (int j = 0; j < 8; j++) qf[t][j] = (__bf16)0.0f;
  }
  if (qd < 2){
    #pragma unroll
    for (int t = 0; t < 4; t++)
      #pragma unroll
      for (int j = 0; j < 8; j++)
        qf[t][j] = (__bf16)Qb[(size_t)(qd * 8 + j) * L + l0 + t * 16 + cn];
  }

  v4f acc[4];
  float den[4] = {0.f, 0.f, 0.f, 0.f};
  #pragma unroll
  for (int t = 0; t < 4; t++) acc[t] = (v4f){0.f, 0.f, 0.f, 0.f};

  for (int ch = 0; ch < 5; ch++){
    int s0 = ch * 512;
    int cnt = (ch == 4) ? 256 : 512;
    __syncthreads();
    {
      // K: one instr = 32 s-rows x 32B; lane i -> s = j*32 + (i>>1), half = i&1
      int per = (cnt >> 5) >> 2;   // 4 or 2 instrs per wave
      for (int jj = 0; jj < per; jj++){
        int j = wave * per + jj;
        int s = j * 32 + (lane >> 1);
        async_cp16(KTb + (size_t)(s0 + s) * C_TOT + c0 + (lane & 1) * 8,
                   Kt + j * 512);
      }
      if (cnt == 512){
        // V: one instr = one 1024B row d; source-side swizzle lane^(d&7)
        #pragma unroll
        for (int jj = 0; jj < 4; jj++){
          int d = wave * 4 + jj;
          async_cp16(Vb + (size_t)d * L + s0 + ((lane ^ (d & 7)) << 3),
                     Vs + d * 512);
        }
      } else {
        // tail: VGPR staging with the same swizzled layout
        int d = tid >> 4, og = tid & 15;
        const __bf16* gp = Vb + (size_t)d * L + s0 + og * 16;
        v8bf v0 = *(const v8bf*)gp;
        v8bf v1 = *(const v8bf*)(gp + 8);
        int pd = d & 7;
        *(v8bf*)&Vs[d * 512 + (((og * 2)     ^ pd) << 3)] = v0;
        *(v8bf*)&Vs[d * 512 + (((og * 2 + 1) ^ pd) << 3)] = v1;
      }
    }
    __syncthreads();

    int nsu = cnt >> 7;                 // 4 or 2
    int wbase = wave * (cnt >> 2);
    for (int su = 0; su < nsu; su++){
      int sb = wbase + su * 32;
      v8bf a0, a1;
      #pragma unroll
      for (int j = 0; j < 8; j++){ a0[j] = (__bf16)0.0f; a1[j] = (__bf16)0.0f; }
      if (qd < 2){
        a0 = *(const v8bf*)&Kt[(sb + cn) * 16 + qd * 8];
        a1 = *(const v8bf*)&Kt[(sb + 16 + cn) * 16 + qd * 8];
      }
      int jv = sb >> 3;
      v8bf vf = *(const v8bf*)&Vs[cn * 512 + (((jv + qd) ^ (cn & 7)) << 3)];
      #pragma unroll
      for (int t = 0; t < 4; t++){
        v4f z = {0.f, 0.f, 0.f, 0.f};
        v4f st0 = MFMA_16x16x32_BF16(a0, qf[t], z);
        v4f st1 = MFMA_16x16x32_BF16(a1, qf[t], z);
        float p0[4], p1[4];
        #pragma unroll
        for (int i = 0; i < 4; i++){
          p0[i] = __expf(st0[i]); den[t] += p0[i];
          p1[i] = __expf(st1[i]); den[t] += p1[i];
        }
        v4bf w0, w1;
        #pragma unroll
        for (int i = 0; i < 4; i++){ w0[i] = (__bf16)p0[i]; w1[i] = (__bf16)p1[i]; }
        *(v4bf*)&Ptw[cn * 40 + qd * 4]      = w0;
        *(v4bf*)&Ptw[cn * 40 + 16 + qd * 4] = w1;
        v8bf pf = *(const v8bf*)&Ptw[cn * 40 + qd * 8];
        acc[t] = MFMA_16x16x32_BF16(vf, pf, acc[t]);
      }
    }
  }

  // cross-wave combine (waves hold disjoint s-ranges of every l-tile)
  __syncthreads();
  float* redA = (float*)smem;            // 4096 floats = 16KB (Kt region)
  float* redD = (float*)(smem + 8192);   // 1024 floats (Vs region)
  #pragma unroll
  for (int t = 0; t < 4; t++){
    *(v4f*)&redA[((wave * 4 + t) * 64 + lane) * 4] = acc[t];
    redD[(wave * 4 + t) * 64 + lane] = den[t];
  }
  __syncthreads();
  {
    int t = wave;
    v4f a = (v4f){0.f, 0.f, 0.f, 0.f};
    float dn = 0.f;
    #pragma unroll
    for (int w2 = 0; w2 < 4; w2++){
      v4f xx = *(const v4f*)&redA[((w2 * 4 + t) * 64 + lane) * 4];
      a[0] += xx[0]; a[1] += xx[1]; a[2] += xx[2]; a[3] += xx[3];
      dn += redD[(w2 * 4 + t) * 64 + lane];
    }
    dn += __shfl_xor(dn, 16);
    dn += __shfl_xor(dn, 32);
    float inv = 1.0f / dn;
    float* Ao = AO + ((size_t)b * C_TOT + c0) * L;
    #pragma unroll
    for (int r2 = 0; r2 < 4; r2++)
      Ao[(size_t)(qd * 4 + r2) * L + l0 + t * 16 + cn] = a[r2] * inv;
  }
}

extern "C" void kernel_launch(void* const* d_in, const int* in_sizes, int n_in,
                              void* d_out, int out_size, void* d_ws, size_t ws_size,
                              hipStream_t stream){
  const float* freq = (const float*)d_in[0];
  const float* spat = (const float*)d_in[1];
  const float* Wq = (const float*)d_in[2]; const float* bq = (const float*)d_in[3];
  const float* Wk = (const float*)d_in[4]; const float* bk = (const float*)d_in[5];
  const float* Wv = (const float*)d_in[6]; const float* bv = (const float*)d_in[7];
  const float* Wo = (const float*)d_in[8]; const float* bo = (const float*)d_in[9];
  float* ws = (float*)d_ws;

  float* SF = ws;                        // 589824 floats
  float* Qb = ws + 589824;
  float* AO = ws + 1179648;
  __bf16* KTg = (__bf16*)(ws + 1769472); // 589824 bf16, layout [b][l][c]
  __bf16* Vg  = (__bf16*)(ws + 2064384); // 589824 bf16, layout [b][c][l]
  float* out = (float*)d_out;

  k_dct2d<<<dim3(256), dim3(256), 0, stream>>>(spat, SF);
  k_proj_qkv<<<dim3(36, 6, 2), dim3(256), 0, stream>>>(freq, SF, Wq, bq, Wk, bk, Wv, bv,
                                                       Qb, KTg, Vg);
  k_attn<<<dim3(36, 16), dim3(256), 0, stream>>>(Qb, KTg, Vg, AO);
  k_proj<<<dim3(36, 2, 2), dim3(256), 0, stream>>>(Wo, bo, AO, out);
}

// Round 7
// 126.135 us; speedup vs baseline: 3.7597x; 1.2303x over previous
//
#include <hip/hip_runtime.h>
#include <math.h>

#define L_TOT 2304
#define C_TOT 128

typedef float v4f  __attribute__((ext_vector_type(4)));
typedef __bf16 v8bf __attribute__((ext_vector_type(8)));
typedef __bf16 v4bf __attribute__((ext_vector_type(4)));

#define MFMA_16x16x32_BF16(A, B, C) __builtin_amdgcn_mfma_f32_16x16x32_bf16((A), (B), (C), 0, 0, 0)

// async 16B/lane global->LDS: LDS dest is wave-uniform base + lane*16 (linear!)
__device__ __forceinline__ void async_cp16(const __bf16* g, __bf16* l){
  __builtin_amdgcn_global_load_lds((const __attribute__((address_space(1))) unsigned int*)g,
                                   (__attribute__((address_space(3))) unsigned int*)l,
                                   16, 0, 0);
}

// ================= split-precision MFMA projection =================
// One 128(M) x 32(N) tile of Y = W(128x128) @ X(128xL) + bias per block.
// W,X fp32 -> hi/lo bf16 split; Y = Whi*Xhi + Whi*Xlo + Wlo*Xhi (fp32-equiv,
// dropped Wlo*Xlo ~ 1e-5 rel). W-frags live in registers (no k0 loop, one
// barrier): block critical path ~1500cyc vs 8-step serial VALU chain before.
// MODE 0: Yf[m][l]=y+b fp32 ; 1: Yh[l][m]=(y+b)*0.25 bf16 (K^T) ; 2: Yh[m][l] bf16 (V)
template<int MODE>
__device__ __forceinline__ void mfma_proj(const float* __restrict__ W,
                                          const float* __restrict__ bias,
                                          const float* __restrict__ Xb,
                                          float* __restrict__ Yf,
                                          __bf16* __restrict__ Yh,
                                          int n0, __bf16* Bhi, int tid){
  __bf16* Blo = Bhi + 4352;            // [32][136] each, pad->bank-uniform
  const int wave = tid >> 6, lane = tid & 63, qd = lane >> 4, cn = lane & 15;
  const int m0 = wave * 32;
  // A-frags (W rows) straight from global, split hi/lo. A[m=cn][k=qd*8+j].
  v8bf ahi[2][4], alo[2][4];
  #pragma unroll
  for (int rt = 0; rt < 2; rt++)
    #pragma unroll
    for (int ks = 0; ks < 4; ks++){
      const float* wp = W + (size_t)(m0 + rt * 16 + cn) * C_TOT + ks * 32 + qd * 8;
      float4 w0 = *(const float4*)wp;
      float4 w1 = *(const float4*)(wp + 4);
      float wv[8] = {w0.x, w0.y, w0.z, w0.w, w1.x, w1.y, w1.z, w1.w};
      #pragma unroll
      for (int j = 0; j < 8; j++){
        __bf16 h = (__bf16)wv[j];
        ahi[rt][ks][j] = h;
        alo[rt][ks][j] = (__bf16)(wv[j] - (float)h);
      }
    }
  // stage X tile (128k x 32n) transposed -> Bs[n][k], split hi/lo
  {
    int k = tid >> 1, nh = tid & 1;
    const float* xp = Xb + (size_t)k * L_TOT + n0 + nh * 16;
    float4 x0 = *(const float4*)xp;
    float4 x1 = *(const float4*)(xp + 4);
    float4 x2 = *(const float4*)(xp + 8);
    float4 x3 = *(const float4*)(xp + 12);
    float xv[16] = {x0.x, x0.y, x0.z, x0.w, x1.x, x1.y, x1.z, x1.w,
                    x2.x, x2.y, x2.z, x2.w, x3.x, x3.y, x3.z, x3.w};
    #pragma unroll
    for (int i = 0; i < 16; i++){
      __bf16 h = (__bf16)xv[i];
      int row = nh * 16 + i;
      Bhi[row * 136 + k] = h;
      Blo[row * 136 + k] = (__bf16)(xv[i] - (float)h);
    }
  }
  __syncthreads();
  v4f acc[2][2];
  #pragma unroll
  for (int rt = 0; rt < 2; rt++)
    #pragma unroll
    for (int ct = 0; ct < 2; ct++) acc[rt][ct] = (v4f){0.f, 0.f, 0.f, 0.f};
  #pragma unroll
  for (int ks = 0; ks < 4; ks++){
    v8bf bhi[2], blo[2];
    #pragma unroll
    for (int ct = 0; ct < 2; ct++){
      bhi[ct] = *(const v8bf*)&Bhi[(ct * 16 + cn) * 136 + ks * 32 + qd * 8];
      blo[ct] = *(const v8bf*)&Blo[(ct * 16 + cn) * 136 + ks * 32 + qd * 8];
    }
    #pragma unroll
    for (int rt = 0; rt < 2; rt++)
      #pragma unroll
      for (int ct = 0; ct < 2; ct++){
        acc[rt][ct] = MFMA_16x16x32_BF16(ahi[rt][ks], bhi[ct], acc[rt][ct]);
        acc[rt][ct] = MFMA_16x16x32_BF16(ahi[rt][ks], blo[ct], acc[rt][ct]);
        acc[rt][ct] = MFMA_16x16x32_BF16(alo[rt][ks], bhi[ct], acc[rt][ct]);
      }
  }
  // epilogue: C/D col=cn(n), row=qd*4+r(m)
  #pragma unroll
  for (int rt = 0; rt < 2; rt++){
    float bv[4];
    #pragma unroll
    for (int r = 0; r < 4; r++) bv[r] = bias[m0 + rt * 16 + qd * 4 + r];
    #pragma unroll
    for (int ct = 0; ct < 2; ct++){
      int col = n0 + ct * 16 + cn;
      if (MODE == 0){
        #pragma unroll
        for (int r = 0; r < 4; r++)
          Yf[(size_t)(m0 + rt * 16 + qd * 4 + r) * L_TOT + col] = acc[rt][ct][r] + bv[r];
      } else if (MODE == 1){
        v4bf kk;
        #pragma unroll
        for (int r = 0; r < 4; r++) kk[r] = (__bf16)((acc[rt][ct][r] + bv[r]) * 0.25f);
        *(v4bf*)&Yh[(size_t)col * C_TOT + m0 + rt * 16 + qd * 4] = kk;
      } else {
        #pragma unroll
        for (int r = 0; r < 4; r++)
          Yh[(size_t)(m0 + rt * 16 + qd * 4 + r) * L_TOT + col] = (__bf16)(acc[rt][ct][r] + bv[r]);
      }
    }
  }
}

// ================= front kernel: DCT (blocks 0..255) || Q-proj (256..399) =================
__global__ __launch_bounds__(256) void k_front(const float* __restrict__ spat,
                                               float* __restrict__ SF,
                                               const float* __restrict__ freq,
                                               const float* __restrict__ Wq,
                                               const float* __restrict__ bq,
                                               float* __restrict__ Qo){
  __shared__ __align__(16) unsigned char smraw[37632];
  int blk = blockIdx.x, tid = threadIdx.x;
  if (blk < 256){
    float* Ds  = (float*)smraw;      // 48x49 padded
    float* DTs = Ds + 2352;
    float* Xs  = Ds + 4704;
    float* Ts  = Ds + 7056;
    const float* Xi = spat + (size_t)blk * 2304;
    float* Fi = SF + (size_t)blk * 2304;
    for (int i = tid; i < 2304; i += 256){
      int k = i / 48, n = i - k * 48;
      int m = ((2 * n + 1) * k) % 192;
      float v = cosf(0.032724923474893679f * (float)m) * 0.204124145231931508f;
      if (k == 0) v *= 0.707106781186547524f;
      Ds[k * 49 + n] = v;
      DTs[n * 49 + k] = v;
      Xs[k * 49 + n] = Xi[i];
    }
    __syncthreads();
    int tr = (tid >> 4) * 3, tc = (tid & 15) * 3;
    {
      float a[3][3] = {};
      for (int n = 0; n < 48; n++){
        float x0 = Xs[tr * 49 + n], x1 = Xs[(tr + 1) * 49 + n], x2 = Xs[(tr + 2) * 49 + n];
        float d0 = DTs[n * 49 + tc], d1 = DTs[n * 49 + tc + 1], d2 = DTs[n * 49 + tc + 2];
        a[0][0] += x0 * d0; a[0][1] += x0 * d1; a[0][2] += x0 * d2;
        a[1][0] += x1 * d0; a[1][1] += x1 * d1; a[1][2] += x1 * d2;
        a[2][0] += x2 * d0; a[2][1] += x2 * d1; a[2][2] += x2 * d2;
      }
      #pragma unroll
      for (int i = 0; i < 3; i++)
        #pragma unroll
        for (int j = 0; j < 3; j++)
          Ts[(tr + i) * 49 + tc + j] = a[i][j];
    }
    __syncthreads();
    {
      float c[3][3] = {};
      for (int m = 0; m < 48; m++){
        float d0 = Ds[tr * 49 + m], d1 = Ds[(tr + 1) * 49 + m], d2 = Ds[(tr + 2) * 49 + m];
        float t0 = Ts[m * 49 + tc], t1 = Ts[m * 49 + tc + 1], t2 = Ts[m * 49 + tc + 2];
        c[0][0] += d0 * t0; c[0][1] += d0 * t1; c[0][2] += d0 * t2;
        c[1][0] += d1 * t0; c[1][1] += d1 * t1; c[1][2] += d1 * t2;
        c[2][0] += d2 * t0; c[2][1] += d2 * t1; c[2][2] += d2 * t2;
      }
      #pragma unroll
      for (int i = 0; i < 3; i++)
        #pragma unroll
        for (int j = 0; j < 3; j++)
          Fi[(tr + i) * 48 + tc + j] = c[i][j];
    }
  } else {
    int idx = blk - 256;               // 0..143
    int b = idx / 72, n0 = (idx % 72) * 32;
    mfma_proj<0>(Wq, bq, freq + (size_t)b * C_TOT * L_TOT,
                 Qo + (size_t)b * C_TOT * L_TOT, (__bf16*)0, n0, (__bf16*)smraw, tid);
  }
}

// ================= K/V projections =================
__global__ __launch_bounds__(256) void k_kv(const float* __restrict__ SF,
                                            const float* __restrict__ Wk, const float* __restrict__ bk,
                                            const float* __restrict__ Wv, const float* __restrict__ bv,
                                            __bf16* __restrict__ KT, __bf16* __restrict__ Vg){
  __shared__ __align__(16) unsigned char smraw[17408];
  int b = blockIdx.z, n0 = blockIdx.x * 32;
  const float* Xb = SF + (size_t)b * C_TOT * L_TOT;
  if (blockIdx.y == 0)
    mfma_proj<1>(Wk, bk, Xb, (float*)0, KT + (size_t)b * L_TOT * C_TOT, n0, (__bf16*)smraw, threadIdx.x);
  else
    mfma_proj<2>(Wv, bv, Xb, (float*)0, Vg + (size_t)b * C_TOT * L_TOT, n0, (__bf16*)smraw, threadIdx.x);
}

// ================= output projection =================
__global__ __launch_bounds__(256) void k_oproj(const float* __restrict__ AO,
                                               const float* __restrict__ Wo, const float* __restrict__ bo,
                                               float* __restrict__ out){
  __shared__ __align__(16) unsigned char smraw[17408];
  int b = blockIdx.y, n0 = blockIdx.x * 32;
  mfma_proj<0>(Wo, bo, AO + (size_t)b * C_TOT * L_TOT,
               out + (size_t)b * C_TOT * L_TOT, (__bf16*)0, n0, (__bf16*)smraw, threadIdx.x);
}

// ================= MFMA flash attention, async-staged (R6, unchanged) =================
__global__ __launch_bounds__(256) void k_attn(const float* __restrict__ Q,
                                              const __bf16* __restrict__ KT,
                                              const __bf16* __restrict__ V,
                                              float* __restrict__ AO){
  const int L = L_TOT;
  int bh = blockIdx.y;
  int b = bh >> 3, h = bh & 7;
  int c0 = h * 16;
  const float*  Qb  = Q  + ((size_t)b * C_TOT + c0) * L;
  const __bf16* KTb = KT + (size_t)b * L * C_TOT;
  const __bf16* Vb  = V  + ((size_t)b * C_TOT + c0) * L;
  int tid = threadIdx.x;
  int wave = tid >> 6, lane = tid & 63;
  int qd = lane >> 4, cn = lane & 15;
  int l0 = blockIdx.x * 64;

  __shared__ __align__(16) __bf16 smem[8192 + 8192 + 2560];
  __bf16* Kt  = smem;
  __bf16* Vs  = smem + 8192;
  __bf16* Ptw = smem + 16384 + wave * 640;

  v8bf qf[4];
  #pragma unroll
  for (int t = 0; t < 4; t++){
    #pragma unroll
    for (int j = 0; j < 8; j++) qf[t][j] = (__bf16)0.0f;
  }
  if (qd < 2){
    #pragma unroll
    for (int t = 0; t < 4; t++)
      #pragma unroll
      for (int j = 0; j < 8; j++)
        qf[t][j] = (__bf16)Qb[(size_t)(qd * 8 + j) * L + l0 + t * 16 + cn];
  }

  v4f acc[4];
  float den[4] = {0.f, 0.f, 0.f, 0.f};
  #pragma unroll
  for (int t = 0; t < 4; t++) acc[t] = (v4f){0.f, 0.f, 0.f, 0.f};

  for (int ch = 0; ch < 5; ch++){
    int s0 = ch * 512;
    int cnt = (ch == 4) ? 256 : 512;
    __syncthreads();
    {
      int per = (cnt >> 5) >> 2;
      for (int jj = 0; jj < per; jj++){
        int j = wave * per + jj;
        int s = j * 32 + (lane >> 1);
        async_cp16(KTb + (size_t)(s0 + s) * C_TOT + c0 + (lane & 1) * 8,
                   Kt + j * 512);
      }
      if (cnt == 512){
        #pragma unroll
        for (int jj = 0; jj < 4; jj++){
          int d = wave * 4 + jj;
          async_cp16(Vb + (size_t)d * L + s0 + ((lane ^ (d & 7)) << 3),
                     Vs + d * 512);
        }
      } else {
        int d = tid >> 4, og = tid & 15;
        const __bf16* gp = Vb + (size_t)d * L + s0 + og * 16;
        v8bf v0 = *(const v8bf*)gp;
        v8bf v1 = *(const v8bf*)(gp + 8);
        int pd = d & 7;
        *(v8bf*)&Vs[d * 512 + (((og * 2)     ^ pd) << 3)] = v0;
        *(v8bf*)&Vs[d * 512 + (((og * 2 + 1) ^ pd) << 3)] = v1;
      }
    }
    __syncthreads();

    int nsu = cnt >> 7;
    int wbase = wave * (cnt >> 2);
    for (int su = 0; su < nsu; su++){
      int sb = wbase + su * 32;
      v8bf a0, a1;
      #pragma unroll
      for (int j = 0; j < 8; j++){ a0[j] = (__bf16)0.0f; a1[j] = (__bf16)0.0f; }
      if (qd < 2){
        a0 = *(const v8bf*)&Kt[(sb + cn) * 16 + qd * 8];
        a1 = *(const v8bf*)&Kt[(sb + 16 + cn) * 16 + qd * 8];
      }
      int jv = sb >> 3;
      v8bf vf = *(const v8bf*)&Vs[cn * 512 + (((jv + qd) ^ (cn & 7)) << 3)];
      #pragma unroll
      for (int t = 0; t < 4; t++){
        v4f z = {0.f, 0.f, 0.f, 0.f};
        v4f st0 = MFMA_16x16x32_BF16(a0, qf[t], z);
        v4f st1 = MFMA_16x16x32_BF16(a1, qf[t], z);
        float p0[4], p1[4];
        #pragma unroll
        for (int i = 0; i < 4; i++){
          p0[i] = __expf(st0[i]); den[t] += p0[i];
          p1[i] = __expf(st1[i]); den[t] += p1[i];
        }
        v4bf w0, w1;
        #pragma unroll
        for (int i = 0; i < 4; i++){ w0[i] = (__bf16)p0[i]; w1[i] = (__bf16)p1[i]; }
        *(v4bf*)&Ptw[cn * 40 + qd * 4]      = w0;
        *(v4bf*)&Ptw[cn * 40 + 16 + qd * 4] = w1;
        v8bf pf = *(const v8bf*)&Ptw[cn * 40 + qd * 8];
        acc[t] = MFMA_16x16x32_BF16(vf, pf, acc[t]);
      }
    }
  }

  __syncthreads();
  float* redA = (float*)smem;
  float* redD = (float*)(smem + 8192);
  #pragma unroll
  for (int t = 0; t < 4; t++){
    *(v4f*)&redA[((wave * 4 + t) * 64 + lane) * 4] = acc[t];
    redD[(wave * 4 + t) * 64 + lane] = den[t];
  }
  __syncthreads();
  {
    int t = wave;
    v4f a = (v4f){0.f, 0.f, 0.f, 0.f};
    float dn = 0.f;
    #pragma unroll
    for (int w2 = 0; w2 < 4; w2++){
      v4f xx = *(const v4f*)&redA[((w2 * 4 + t) * 64 + lane) * 4];
      a[0] += xx[0]; a[1] += xx[1]; a[2] += xx[2]; a[3] += xx[3];
      dn += redD[(w2 * 4 + t) * 64 + lane];
    }
    dn += __shfl_xor(dn, 16);
    dn += __shfl_xor(dn, 32);
    float inv = 1.0f / dn;
    float* Ao = AO + ((size_t)b * C_TOT + c0) * L;
    #pragma unroll
    for (int r2 = 0; r2 < 4; r2++)
      Ao[(size_t)(qd * 4 + r2) * L + l0 + t * 16 + cn] = a[r2] * inv;
  }
}

extern "C" void kernel_launch(void* const* d_in, const int* in_sizes, int n_in,
                              void* d_out, int out_size, void* d_ws, size_t ws_size,
                              hipStream_t stream){
  const float* freq = (const float*)d_in[0];
  const float* spat = (const float*)d_in[1];
  const float* Wq = (const float*)d_in[2]; const float* bq = (const float*)d_in[3];
  const float* Wk = (const float*)d_in[4]; const float* bk = (const float*)d_in[5];
  const float* Wv = (const float*)d_in[6]; const float* bv = (const float*)d_in[7];
  const float* Wo = (const float*)d_in[8]; const float* bo = (const float*)d_in[9];
  float* ws = (float*)d_ws;

  float* SF = ws;                        // 589824 floats
  float* Qb = ws + 589824;
  float* AO = ws + 1179648;
  __bf16* KTg = (__bf16*)(ws + 1769472); // bf16 [b][l][c]
  __bf16* Vg  = (__bf16*)(ws + 2064384); // bf16 [b][c][l]
  float* out = (float*)d_out;

  k_front<<<dim3(400), dim3(256), 0, stream>>>(spat, SF, freq, Wq, bq, Qb);
  k_kv<<<dim3(72, 2, 2), dim3(256), 0, stream>>>(SF, Wk, bk, Wv, bv, KTg, Vg);
  k_attn<<<dim3(36, 16), dim3(256), 0, stream>>>(Qb, KTg, Vg, AO);
  k_oproj<<<dim3(72, 2), dim3(256), 0, stream>>>(AO, Wo, bo, out);
}

// Round 8
// 124.644 us; speedup vs baseline: 3.8046x; 1.0120x over previous
//
#include <hip/hip_runtime.h>
#include <math.h>

#define L_TOT 2304
#define C_TOT 128

typedef float v4f  __attribute__((ext_vector_type(4)));
typedef __bf16 v8bf __attribute__((ext_vector_type(8)));
typedef __bf16 v4bf __attribute__((ext_vector_type(4)));

#define MFMA_16x16x32_BF16(A, B, C) __builtin_amdgcn_mfma_f32_16x16x32_bf16((A), (B), (C), 0, 0, 0)

// async 16B/lane global->LDS: LDS dest is wave-uniform base + lane*16 (linear!)
__device__ __forceinline__ void async_cp16(const __bf16* g, __bf16* l){
  __builtin_amdgcn_global_load_lds((const __attribute__((address_space(1))) unsigned int*)g,
                                   (__attribute__((address_space(3))) unsigned int*)l,
                                   16, 0, 0);
}

// ================= split-precision MFMA projection =================
// One 128(M) x 32(N) tile of Y = W(128x128) @ X(128xL) + bias per block.
// W,X fp32 -> hi/lo bf16; Y = Whi*Xhi + Whi*Xlo + Wlo*Xhi (fp32-equiv).
// MODE 0: Yf[m][l] fp32 ; 1: Yh[l][m] bf16 transposed, *scale (K^T, Q^T) ; 2: Yh[m][l] bf16 (V)
template<int MODE>
__device__ __forceinline__ void mfma_proj(const float* __restrict__ W,
                                          const float* __restrict__ bias,
                                          const float* __restrict__ Xb,
                                          float* __restrict__ Yf,
                                          __bf16* __restrict__ Yh,
                                          float scale,
                                          int n0, __bf16* Bhi, int tid){
  __bf16* Blo = Bhi + 4352;            // [32][136] each, pad->bank-uniform
  const int wave = tid >> 6, lane = tid & 63, qd = lane >> 4, cn = lane & 15;
  const int m0 = wave * 32;
  v8bf ahi[2][4], alo[2][4];
  #pragma unroll
  for (int rt = 0; rt < 2; rt++)
    #pragma unroll
    for (int ks = 0; ks < 4; ks++){
      const float* wp = W + (size_t)(m0 + rt * 16 + cn) * C_TOT + ks * 32 + qd * 8;
      float4 w0 = *(const float4*)wp;
      float4 w1 = *(const float4*)(wp + 4);
      float wv[8] = {w0.x, w0.y, w0.z, w0.w, w1.x, w1.y, w1.z, w1.w};
      #pragma unroll
      for (int j = 0; j < 8; j++){
        __bf16 h = (__bf16)wv[j];
        ahi[rt][ks][j] = h;
        alo[rt][ks][j] = (__bf16)(wv[j] - (float)h);
      }
    }
  {
    int k = tid >> 1, nh = tid & 1;
    const float* xp = Xb + (size_t)k * L_TOT + n0 + nh * 16;
    float4 x0 = *(const float4*)xp;
    float4 x1 = *(const float4*)(xp + 4);
    float4 x2 = *(const float4*)(xp + 8);
    float4 x3 = *(const float4*)(xp + 12);
    float xv[16] = {x0.x, x0.y, x0.z, x0.w, x1.x, x1.y, x1.z, x1.w,
                    x2.x, x2.y, x2.z, x2.w, x3.x, x3.y, x3.z, x3.w};
    #pragma unroll
    for (int i = 0; i < 16; i++){
      __bf16 h = (__bf16)xv[i];
      int row = nh * 16 + i;
      Bhi[row * 136 + k] = h;
      Blo[row * 136 + k] = (__bf16)(xv[i] - (float)h);
    }
  }
  __syncthreads();
  v4f acc[2][2];
  #pragma unroll
  for (int rt = 0; rt < 2; rt++)
    #pragma unroll
    for (int ct = 0; ct < 2; ct++) acc[rt][ct] = (v4f){0.f, 0.f, 0.f, 0.f};
  #pragma unroll
  for (int ks = 0; ks < 4; ks++){
    v8bf bhi[2], blo[2];
    #pragma unroll
    for (int ct = 0; ct < 2; ct++){
      bhi[ct] = *(const v8bf*)&Bhi[(ct * 16 + cn) * 136 + ks * 32 + qd * 8];
      blo[ct] = *(const v8bf*)&Blo[(ct * 16 + cn) * 136 + ks * 32 + qd * 8];
    }
    #pragma unroll
    for (int rt = 0; rt < 2; rt++)
      #pragma unroll
      for (int ct = 0; ct < 2; ct++){
        acc[rt][ct] = MFMA_16x16x32_BF16(ahi[rt][ks], bhi[ct], acc[rt][ct]);
        acc[rt][ct] = MFMA_16x16x32_BF16(ahi[rt][ks], blo[ct], acc[rt][ct]);
        acc[rt][ct] = MFMA_16x16x32_BF16(alo[rt][ks], bhi[ct], acc[rt][ct]);
      }
  }
  #pragma unroll
  for (int rt = 0; rt < 2; rt++){
    float bv[4];
    #pragma unroll
    for (int r = 0; r < 4; r++) bv[r] = bias[m0 + rt * 16 + qd * 4 + r];
    #pragma unroll
    for (int ct = 0; ct < 2; ct++){
      int col = n0 + ct * 16 + cn;
      if (MODE == 0){
        #pragma unroll
        for (int r = 0; r < 4; r++)
          Yf[(size_t)(m0 + rt * 16 + qd * 4 + r) * L_TOT + col] = acc[rt][ct][r] + bv[r];
      } else if (MODE == 1){
        v4bf kk;
        #pragma unroll
        for (int r = 0; r < 4; r++) kk[r] = (__bf16)((acc[rt][ct][r] + bv[r]) * scale);
        *(v4bf*)&Yh[(size_t)col * C_TOT + m0 + rt * 16 + qd * 4] = kk;
      } else {
        #pragma unroll
        for (int r = 0; r < 4; r++)
          Yh[(size_t)(m0 + rt * 16 + qd * 4 + r) * L_TOT + col] = (__bf16)(acc[rt][ct][r] + bv[r]);
      }
    }
  }
}

// ================= front kernel: DCT (blocks 0..255) || Q^T-proj (256..399) =================
__global__ __launch_bounds__(256) void k_front(const float* __restrict__ spat,
                                               float* __restrict__ SF,
                                               const float* __restrict__ freq,
                                               const float* __restrict__ Wq,
                                               const float* __restrict__ bq,
                                               __bf16* __restrict__ QT){
  __shared__ __align__(16) unsigned char smraw[37632];
  int blk = blockIdx.x, tid = threadIdx.x;
  if (blk < 256){
    float* Ds  = (float*)smraw;      // 48x49 padded
    float* DTs = Ds + 2352;
    float* Xs  = Ds + 4704;
    float* Ts  = Ds + 7056;
    const float* Xi = spat + (size_t)blk * 2304;
    float* Fi = SF + (size_t)blk * 2304;
    for (int i = tid; i < 2304; i += 256){
      int k = i / 48, n = i - k * 48;
      int m = ((2 * n + 1) * k) % 192;
      float v = cosf(0.032724923474893679f * (float)m) * 0.204124145231931508f;
      if (k == 0) v *= 0.707106781186547524f;
      Ds[k * 49 + n] = v;
      DTs[n * 49 + k] = v;
      Xs[k * 49 + n] = Xi[i];
    }
    __syncthreads();
    int tr = (tid >> 4) * 3, tc = (tid & 15) * 3;
    {
      float a[3][3] = {};
      for (int n = 0; n < 48; n++){
        float x0 = Xs[tr * 49 + n], x1 = Xs[(tr + 1) * 49 + n], x2 = Xs[(tr + 2) * 49 + n];
        float d0 = DTs[n * 49 + tc], d1 = DTs[n * 49 + tc + 1], d2 = DTs[n * 49 + tc + 2];
        a[0][0] += x0 * d0; a[0][1] += x0 * d1; a[0][2] += x0 * d2;
        a[1][0] += x1 * d0; a[1][1] += x1 * d1; a[1][2] += x1 * d2;
        a[2][0] += x2 * d0; a[2][1] += x2 * d1; a[2][2] += x2 * d2;
      }
      #pragma unroll
      for (int i = 0; i < 3; i++)
        #pragma unroll
        for (int j = 0; j < 3; j++)
          Ts[(tr + i) * 49 + tc + j] = a[i][j];
    }
    __syncthreads();
    {
      float c[3][3] = {};
      for (int m = 0; m < 48; m++){
        float d0 = Ds[tr * 49 + m], d1 = Ds[(tr + 1) * 49 + m], d2 = Ds[(tr + 2) * 49 + m];
        float t0 = Ts[m * 49 + tc], t1 = Ts[m * 49 + tc + 1], t2 = Ts[m * 49 + tc + 2];
        c[0][0] += d0 * t0; c[0][1] += d0 * t1; c[0][2] += d0 * t2;
        c[1][0] += d1 * t0; c[1][1] += d1 * t1; c[1][2] += d1 * t2;
        c[2][0] += d2 * t0; c[2][1] += d2 * t1; c[2][2] += d2 * t2;
      }
      #pragma unroll
      for (int i = 0; i < 3; i++)
        #pragma unroll
        for (int j = 0; j < 3; j++)
          Fi[(tr + i) * 48 + tc + j] = c[i][j];
    }
  } else {
    int idx = blk - 256;               // 0..143
    int b = idx / 72, n0 = (idx % 72) * 32;
    mfma_proj<1>(Wq, bq, freq + (size_t)b * C_TOT * L_TOT,
                 (float*)0, QT + (size_t)b * L_TOT * C_TOT, 1.0f, n0, (__bf16*)smraw, tid);
  }
}

// ================= K/V projections =================
__global__ __launch_bounds__(256) void k_kv(const float* __restrict__ SF,
                                            const float* __restrict__ Wk, const float* __restrict__ bk,
                                            const float* __restrict__ Wv, const float* __restrict__ bv,
                                            __bf16* __restrict__ KT, __bf16* __restrict__ Vg){
  __shared__ __align__(16) unsigned char smraw[17408];
  int b = blockIdx.z, n0 = blockIdx.x * 32;
  const float* Xb = SF + (size_t)b * C_TOT * L_TOT;
  if (blockIdx.y == 0)
    mfma_proj<1>(Wk, bk, Xb, (float*)0, KT + (size_t)b * L_TOT * C_TOT, 0.25f, n0, (__bf16*)smraw, threadIdx.x);
  else
    mfma_proj<2>(Wv, bv, Xb, (float*)0, Vg + (size_t)b * C_TOT * L_TOT, 1.0f, n0, (__bf16*)smraw, threadIdx.x);
}

// ================= output projection (bf16 B, W split in regs) =================
__global__ __launch_bounds__(256) void k_oproj(const __bf16* __restrict__ AO,
                                               const float* __restrict__ Wo, const float* __restrict__ bo,
                                               float* __restrict__ out){
  __shared__ __align__(16) __bf16 Bs[32 * 136];   // 8704 B
  int b = blockIdx.y, n0 = blockIdx.x * 32;
  int tid = threadIdx.x;
  const int wave = tid >> 6, lane = tid & 63, qd = lane >> 4, cn = lane & 15;
  const int m0 = wave * 32;
  v8bf ahi[2][4], alo[2][4];
  #pragma unroll
  for (int rt = 0; rt < 2; rt++)
    #pragma unroll
    for (int ks = 0; ks < 4; ks++){
      const float* wp = Wo + (size_t)(m0 + rt * 16 + cn) * C_TOT + ks * 32 + qd * 8;
      float4 w0 = *(const float4*)wp;
      float4 w1 = *(const float4*)(wp + 4);
      float wv[8] = {w0.x, w0.y, w0.z, w0.w, w1.x, w1.y, w1.z, w1.w};
      #pragma unroll
      for (int j = 0; j < 8; j++){
        __bf16 h = (__bf16)wv[j];
        ahi[rt][ks][j] = h;
        alo[rt][ks][j] = (__bf16)(wv[j] - (float)h);
      }
    }
  {
    int k = tid >> 1, nh = tid & 1;
    const __bf16* src = AO + ((size_t)b * C_TOT + k) * L_TOT + n0 + nh * 16;
    v8bf x0 = *(const v8bf*)src;
    v8bf x1 = *(const v8bf*)(src + 8);
    #pragma unroll
    for (int i = 0; i < 8; i++){
      Bs[(nh * 16 + i) * 136 + k] = x0[i];
      Bs[(nh * 16 + 8 + i) * 136 + k] = x1[i];
    }
  }
  __syncthreads();
  v4f acc[2][2];
  #pragma unroll
  for (int rt = 0; rt < 2; rt++)
    #pragma unroll
    for (int ct = 0; ct < 2; ct++) acc[rt][ct] = (v4f){0.f, 0.f, 0.f, 0.f};
  #pragma unroll
  for (int ks = 0; ks < 4; ks++){
    v8bf bf[2];
    #pragma unroll
    for (int ct = 0; ct < 2; ct++)
      bf[ct] = *(const v8bf*)&Bs[(ct * 16 + cn) * 136 + ks * 32 + qd * 8];
    #pragma unroll
    for (int rt = 0; rt < 2; rt++)
      #pragma unroll
      for (int ct = 0; ct < 2; ct++){
        acc[rt][ct] = MFMA_16x16x32_BF16(ahi[rt][ks], bf[ct], acc[rt][ct]);
        acc[rt][ct] = MFMA_16x16x32_BF16(alo[rt][ks], bf[ct], acc[rt][ct]);
      }
  }
  float* ob = out + (size_t)b * C_TOT * L_TOT;
  #pragma unroll
  for (int rt = 0; rt < 2; rt++){
    float bv[4];
    #pragma unroll
    for (int r = 0; r < 4; r++) bv[r] = bo[m0 + rt * 16 + qd * 4 + r];
    #pragma unroll
    for (int ct = 0; ct < 2; ct++){
      int col = n0 + ct * 16 + cn;
      #pragma unroll
      for (int r = 0; r < 4; r++)
        ob[(size_t)(m0 + rt * 16 + qd * 4 + r) * L_TOT + col] = acc[rt][ct][r] + bv[r];
    }
  }
}

// ================= MFMA flash attention, async-staged =================
__global__ __launch_bounds__(256) void k_attn(const __bf16* __restrict__ QT,
                                              const __bf16* __restrict__ KT,
                                              const __bf16* __restrict__ V,
                                              __bf16* __restrict__ AO){
  const int L = L_TOT;
  int bh = blockIdx.y;
  int b = bh >> 3, h = bh & 7;
  int c0 = h * 16;
  const __bf16* QTb = QT + (size_t)b * L * C_TOT;
  const __bf16* KTb = KT + (size_t)b * L * C_TOT;
  const __bf16* Vb  = V  + ((size_t)b * C_TOT + c0) * L;
  int tid = threadIdx.x;
  int wave = tid >> 6, lane = tid & 63;
  int qd = lane >> 4, cn = lane & 15;
  int l0 = blockIdx.x * 64;

  __shared__ __align__(16) __bf16 smem[8192 + 8192 + 2560];
  __bf16* Kt  = smem;
  __bf16* Vs  = smem + 8192;
  __bf16* Ptw = smem + 16384 + wave * 640;

  // Q B-frags direct from QT[l][c] bf16 (quads 2,3 zero: d padded 16->32)
  v8bf qf[4];
  #pragma unroll
  for (int t = 0; t < 4; t++){
    #pragma unroll
    for (int j = 0; j < 8; j++) qf[t][j] = (__bf16)0.0f;
  }
  if (qd < 2){
    #pragma unroll
    for (int t = 0; t < 4; t++)
      qf[t] = *(const v8bf*)&QTb[(size_t)(l0 + t * 16 + cn) * C_TOT + c0 + qd * 8];
  }

  v4f acc[4];
  float den[4] = {0.f, 0.f, 0.f, 0.f};
  #pragma unroll
  for (int t = 0; t < 4; t++) acc[t] = (v4f){0.f, 0.f, 0.f, 0.f};

  for (int ch = 0; ch < 5; ch++){
    int s0 = ch * 512;
    int cnt = (ch == 4) ? 256 : 512;
    __syncthreads();
    {
      int per = (cnt >> 5) >> 2;
      for (int jj = 0; jj < per; jj++){
        int j = wave * per + jj;
        int s = j * 32 + (lane >> 1);
        async_cp16(KTb + (size_t)(s0 + s) * C_TOT + c0 + (lane & 1) * 8,
                   Kt + j * 512);
      }
      if (cnt == 512){
        #pragma unroll
        for (int jj = 0; jj < 4; jj++){
          int d = wave * 4 + jj;
          async_cp16(Vb + (size_t)d * L + s0 + ((lane ^ (d & 7)) << 3),
                     Vs + d * 512);
        }
      } else {
        int d = tid >> 4, og = tid & 15;
        const __bf16* gp = Vb + (size_t)d * L + s0 + og * 16;
        v8bf v0 = *(const v8bf*)gp;
        v8bf v1 = *(const v8bf*)(gp + 8);
        int pd = d & 7;
        *(v8bf*)&Vs[d * 512 + (((og * 2)     ^ pd) << 3)] = v0;
        *(v8bf*)&Vs[d * 512 + (((og * 2 + 1) ^ pd) << 3)] = v1;
      }
    }
    __syncthreads();

    int nsu = cnt >> 7;
    int wbase = wave * (cnt >> 2);
    for (int su = 0; su < nsu; su++){
      int sb = wbase + su * 32;
      v8bf a0, a1;
      #pragma unroll
      for (int j = 0; j < 8; j++){ a0[j] = (__bf16)0.0f; a1[j] = (__bf16)0.0f; }
      if (qd < 2){
        a0 = *(const v8bf*)&Kt[(sb + cn) * 16 + qd * 8];
        a1 = *(const v8bf*)&Kt[(sb + 16 + cn) * 16 + qd * 8];
      }
      int jv = sb >> 3;
      v8bf vf = *(const v8bf*)&Vs[cn * 512 + (((jv + qd) ^ (cn & 7)) << 3)];
      #pragma unroll
      for (int t = 0; t < 4; t++){
        v4f z = {0.f, 0.f, 0.f, 0.f};
        v4f st0 = MFMA_16x16x32_BF16(a0, qf[t], z);
        v4f st1 = MFMA_16x16x32_BF16(a1, qf[t], z);
        float p0[4], p1[4];
        #pragma unroll
        for (int i = 0; i < 4; i++){
          p0[i] = __expf(st0[i]); den[t] += p0[i];
          p1[i] = __expf(st1[i]); den[t] += p1[i];
        }
        v4bf w0, w1;
        #pragma unroll
        for (int i = 0; i < 4; i++){ w0[i] = (__bf16)p0[i]; w1[i] = (__bf16)p1[i]; }
        *(v4bf*)&Ptw[cn * 40 + qd * 4]      = w0;
        *(v4bf*)&Ptw[cn * 40 + 16 + qd * 4] = w1;
        v8bf pf = *(const v8bf*)&Ptw[cn * 40 + qd * 8];
        acc[t] = MFMA_16x16x32_BF16(vf, pf, acc[t]);
      }
    }
  }

  __syncthreads();
  float* redA = (float*)smem;
  float* redD = (float*)(smem + 8192);
  #pragma unroll
  for (int t = 0; t < 4; t++){
    *(v4f*)&redA[((wave * 4 + t) * 64 + lane) * 4] = acc[t];
    redD[(wave * 4 + t) * 64 + lane] = den[t];
  }
  __syncthreads();
  {
    int t = wave;
    v4f a = (v4f){0.f, 0.f, 0.f, 0.f};
    float dn = 0.f;
    #pragma unroll
    for (int w2 = 0; w2 < 4; w2++){
      v4f xx = *(const v4f*)&redA[((w2 * 4 + t) * 64 + lane) * 4];
      a[0] += xx[0]; a[1] += xx[1]; a[2] += xx[2]; a[3] += xx[3];
      dn += redD[(w2 * 4 + t) * 64 + lane];
    }
    dn += __shfl_xor(dn, 16);
    dn += __shfl_xor(dn, 32);
    float inv = 1.0f / dn;
    __bf16* Ao = AO + ((size_t)b * C_TOT + c0) * L;
    #pragma unroll
    for (int r2 = 0; r2 < 4; r2++)
      Ao[(size_t)(qd * 4 + r2) * L + l0 + t * 16 + cn] = (__bf16)(a[r2] * inv);
  }
}

extern "C" void kernel_launch(void* const* d_in, const int* in_sizes, int n_in,
                              void* d_out, int out_size, void* d_ws, size_t ws_size,
                              hipStream_t stream){
  const float* freq = (const float*)d_in[0];
  const float* spat = (const float*)d_in[1];
  const float* Wq = (const float*)d_in[2]; const float* bq = (const float*)d_in[3];
  const float* Wk = (const float*)d_in[4]; const float* bk = (const float*)d_in[5];
  const float* Wv = (const float*)d_in[6]; const float* bv = (const float*)d_in[7];
  const float* Wo = (const float*)d_in[8]; const float* bo = (const float*)d_in[9];
  float* ws = (float*)d_ws;

  float* SF   = ws;                        // 589824 fp32
  __bf16* QTg = (__bf16*)(ws + 589824);    // 589824 bf16 [b][l][c]
  __bf16* AOg = (__bf16*)(ws + 884736);    // 589824 bf16 [b][c][l]
  __bf16* KTg = (__bf16*)(ws + 1179648);   // 589824 bf16 [b][l][c], pre-scaled 0.25
  __bf16* Vg  = (__bf16*)(ws + 1474560);   // 589824 bf16 [b][c][l]
  float* out = (float*)d_out;

  k_front<<<dim3(400), dim3(256), 0, stream>>>(spat, SF, freq, Wq, bq, QTg);
  k_kv<<<dim3(72, 2, 2), dim3(256), 0, stream>>>(SF, Wk, bk, Wv, bv, KTg, Vg);
  k_attn<<<dim3(36, 16), dim3(256), 0, stream>>>(QTg, KTg, Vg, AOg);
  k_oproj<<<dim3(72, 2), dim3(256), 0, stream>>>(AOg, Wo, bo, out);
}

// Round 9
// 121.802 us; speedup vs baseline: 3.8934x; 1.0233x over previous
//
#include <hip/hip_runtime.h>
#include <math.h>

#define L_TOT 2304
#define C_TOT 128
// fold 1/ln2 into K so softmax uses native exp2
#define KSCALE 0.36067376022224085f   // 0.25 * log2(e)

#if __has_builtin(__builtin_amdgcn_exp2f)
#define EXP2(x) __builtin_amdgcn_exp2f(x)
#else
#define EXP2(x) __expf(0.69314718055994531f * (x))
#endif

typedef float v4f  __attribute__((ext_vector_type(4)));
typedef __bf16 v8bf __attribute__((ext_vector_type(8)));
typedef __bf16 v4bf __attribute__((ext_vector_type(4)));

#define MFMA_16x16x32_BF16(A, B, C) __builtin_amdgcn_mfma_f32_16x16x32_bf16((A), (B), (C), 0, 0, 0)

// async 16B/lane global->LDS: LDS dest is wave-uniform base + lane*16 (linear!)
__device__ __forceinline__ void async_cp16(const __bf16* g, __bf16* l){
  __builtin_amdgcn_global_load_lds((const __attribute__((address_space(1))) unsigned int*)g,
                                   (__attribute__((address_space(3))) unsigned int*)l,
                                   16, 0, 0);
}

// ================= split-precision MFMA projection =================
// One 128(M) x 32(N) tile of Y = W @ X + bscale*bias per block.
// W,X fp32 -> hi/lo bf16; Y = Whi*Xhi + Whi*Xlo + Wlo*Xhi (fp32-equiv).
// MODE 1: Yh[l][m] bf16 transposed, *scale ; 2: Yh[m][l] bf16
template<int MODE>
__device__ __forceinline__ void mfma_proj(const float* __restrict__ W,
                                          const float* __restrict__ bias,
                                          const float* __restrict__ Xb,
                                          __bf16* __restrict__ Yh,
                                          float scale, float bscale,
                                          int n0, __bf16* Bhi, int tid){
  __bf16* Blo = Bhi + 4352;            // [32][136] each, pad->bank-uniform
  const int wave = tid >> 6, lane = tid & 63, qd = lane >> 4, cn = lane & 15;
  const int m0 = wave * 32;
  v8bf ahi[2][4], alo[2][4];
  #pragma unroll
  for (int rt = 0; rt < 2; rt++)
    #pragma unroll
    for (int ks = 0; ks < 4; ks++){
      const float* wp = W + (size_t)(m0 + rt * 16 + cn) * C_TOT + ks * 32 + qd * 8;
      float4 w0 = *(const float4*)wp;
      float4 w1 = *(const float4*)(wp + 4);
      float wv[8] = {w0.x, w0.y, w0.z, w0.w, w1.x, w1.y, w1.z, w1.w};
      #pragma unroll
      for (int j = 0; j < 8; j++){
        __bf16 h = (__bf16)wv[j];
        ahi[rt][ks][j] = h;
        alo[rt][ks][j] = (__bf16)(wv[j] - (float)h);
      }
    }
  {
    int k = tid >> 1, nh = tid & 1;
    const float* xp = Xb + (size_t)k * L_TOT + n0 + nh * 16;
    float4 x0 = *(const float4*)xp;
    float4 x1 = *(const float4*)(xp + 4);
    float4 x2 = *(const float4*)(xp + 8);
    float4 x3 = *(const float4*)(xp + 12);
    float xv[16] = {x0.x, x0.y, x0.z, x0.w, x1.x, x1.y, x1.z, x1.w,
                    x2.x, x2.y, x2.z, x2.w, x3.x, x3.y, x3.z, x3.w};
    #pragma unroll
    for (int i = 0; i < 16; i++){
      __bf16 h = (__bf16)xv[i];
      int row = nh * 16 + i;
      Bhi[row * 136 + k] = h;
      Blo[row * 136 + k] = (__bf16)(xv[i] - (float)h);
    }
  }
  __syncthreads();
  v4f acc[2][2];
  #pragma unroll
  for (int rt = 0; rt < 2; rt++)
    #pragma unroll
    for (int ct = 0; ct < 2; ct++) acc[rt][ct] = (v4f){0.f, 0.f, 0.f, 0.f};
  #pragma unroll
  for (int ks = 0; ks < 4; ks++){
    v8bf bhi[2], blo[2];
    #pragma unroll
    for (int ct = 0; ct < 2; ct++){
      bhi[ct] = *(const v8bf*)&Bhi[(ct * 16 + cn) * 136 + ks * 32 + qd * 8];
      blo[ct] = *(const v8bf*)&Blo[(ct * 16 + cn) * 136 + ks * 32 + qd * 8];
    }
    #pragma unroll
    for (int rt = 0; rt < 2; rt++)
      #pragma unroll
      for (int ct = 0; ct < 2; ct++){
        acc[rt][ct] = MFMA_16x16x32_BF16(ahi[rt][ks], bhi[ct], acc[rt][ct]);
        acc[rt][ct] = MFMA_16x16x32_BF16(ahi[rt][ks], blo[ct], acc[rt][ct]);
        acc[rt][ct] = MFMA_16x16x32_BF16(alo[rt][ks], bhi[ct], acc[rt][ct]);
      }
  }
  #pragma unroll
  for (int rt = 0; rt < 2; rt++){
    float bv[4];
    #pragma unroll
    for (int r = 0; r < 4; r++) bv[r] = bias[m0 + rt * 16 + qd * 4 + r] * bscale;
    #pragma unroll
    for (int ct = 0; ct < 2; ct++){
      int col = n0 + ct * 16 + cn;
      if (MODE == 1){
        v4bf kk;
        #pragma unroll
        for (int r = 0; r < 4; r++) kk[r] = (__bf16)((acc[rt][ct][r] + bv[r]) * scale);
        *(v4bf*)&Yh[(size_t)col * C_TOT + m0 + rt * 16 + qd * 4] = kk;
      } else {
        #pragma unroll
        for (int r = 0; r < 4; r++)
          Yh[(size_t)(m0 + rt * 16 + qd * 4 + r) * L_TOT + col] = (__bf16)(acc[rt][ct][r] + bv[r]);
      }
    }
  }
}

// ================= stage 1: Q,K,V projections (no deps; DCT commuted past proj) =================
// job 0: Q^T from freq (bias now). job 1/2: Kraw/Vraw [c][l] from spat, bias DEFERRED
// (DCT(A + b*1) != DCT(A) + b -> bias added after DCT in k_dct_kv).
__global__ __launch_bounds__(256) void k_qkv(
    const float* __restrict__ freq, const float* __restrict__ spat,
    const float* __restrict__ Wq, const float* __restrict__ bq,
    const float* __restrict__ Wk, const float* __restrict__ bk,
    const float* __restrict__ Wv, const float* __restrict__ bv,
    __bf16* __restrict__ QT, __bf16* __restrict__ Kraw, __bf16* __restrict__ Vraw){
  __shared__ __align__(16) unsigned char smraw[17408];
  int job = blockIdx.x / 144;
  int idx = blockIdx.x % 144;
  int b = idx / 72, n0 = (idx % 72) * 32;
  size_t off = (size_t)b * C_TOT * L_TOT;
  if (job == 0)
    mfma_proj<1>(Wq, bq, freq + off, QT + (size_t)b * L_TOT * C_TOT, 1.0f, 1.0f, n0, (__bf16*)smraw, threadIdx.x);
  else if (job == 1)
    mfma_proj<2>(Wk, bk, spat + off, Kraw + off, 1.0f, 0.0f, n0, (__bf16*)smraw, threadIdx.x);
  else
    mfma_proj<2>(Wv, bv, spat + off, Vraw + off, 1.0f, 0.0f, n0, (__bf16*)smraw, threadIdx.x);
}

// ================= stage 2: MFMA 2D-DCT on Kraw/Vraw images =================
// Block = one 48x48 image (512 total: 256 K + 256 V). F = D*X*D^T via two
// MFMA passes (K=48 padded to 64; pads zeroed so garbage can't inject NaN).
// T round-trips LDS transposed (b64 C/D writes; 72-elem rows -> <=2-way conflicts).
// K out: KT[l][c] scaled KSCALE, +bk. V out: V[c][l], +bv.
__global__ __launch_bounds__(256) void k_dct_kv(const __bf16* __restrict__ Kraw,
                                                const __bf16* __restrict__ Vraw,
                                                const float* __restrict__ bk,
                                                const float* __restrict__ bv,
                                                __bf16* __restrict__ KT,
                                                __bf16* __restrict__ Vg){
  __shared__ __align__(16) __bf16 Xs[3456];   // [48][72]
  __shared__ __align__(16) __bf16 Dm[3456];   // D[a][n], rows padded
  __shared__ __align__(16) __bf16 Tt[3456];   // T^T[w][m]
  int blk = blockIdx.x, tid = threadIdx.x;
  int isV = blk >> 8;
  int img = blk & 255;
  int b = img >> 7, c = img & 127;
  const __bf16* src = (isV ? Vraw : Kraw) + (size_t)img * 2304;
  float bias = (isV ? bv : bk)[c];
  for (int i = tid; i < 1728; i += 256){
    ((unsigned int*)Xs)[i] = 0u;
    ((unsigned int*)Dm)[i] = 0u;
    ((unsigned int*)Tt)[i] = 0u;
  }
  __syncthreads();
  for (int i = tid; i < 2304; i += 256){
    int a = i / 48, n = i - a * 48;
    int m = ((2 * n + 1) * a) % 192;      // exact angle reduction, cos period = 192
    float v = cosf(0.032724923474893679f * (float)m) * 0.204124145231931508f;
    if (a == 0) v *= 0.707106781186547524f;
    Dm[a * 72 + n] = (__bf16)v;
  }
  for (int t = tid; t < 288; t += 256){    // rows are 6 v8bf each (48 = 6*8)
    int m = t / 6, j = t - m * 6;
    *(v8bf*)&Xs[m * 72 + j * 8] = *(const v8bf*)(src + t * 8);
  }
  __syncthreads();
  int wave = tid >> 6, lane = tid & 63, qd = lane >> 4, cn = lane & 15;
  // pass 1: T[m][w] = sum_n X[m][n] D[w][n]  (A=X rows m, B=D rows w along n)
  for (int t = wave; t < 9; t += 4){
    int mi = t / 3, wi = t - mi * 3;
    v8bf a0 = *(const v8bf*)&Xs[(mi * 16 + cn) * 72 + qd * 8];
    v8bf a1 = *(const v8bf*)&Xs[(mi * 16 + cn) * 72 + 32 + qd * 8];
    v8bf b0 = *(const v8bf*)&Dm[(wi * 16 + cn) * 72 + qd * 8];
    v8bf b1 = *(const v8bf*)&Dm[(wi * 16 + cn) * 72 + 32 + qd * 8];
    v4f acc = (v4f){0.f, 0.f, 0.f, 0.f};
    acc = MFMA_16x16x32_BF16(a0, b0, acc);
    acc = MFMA_16x16x32_BF16(a1, b1, acc);
    v4bf w4;
    #pragma unroll
    for (int r = 0; r < 4; r++) w4[r] = (__bf16)acc[r];
    *(v4bf*)&Tt[(wi * 16 + cn) * 72 + mi * 16 + qd * 4] = w4;   // col=w, rows m
  }
  __syncthreads();
  // pass 2: F[h][w] = sum_m D[h][m] T[m][w]  (A=D rows h, B=T^T rows w along m)
  for (int t = wave; t < 9; t += 4){
    int hi = t / 3, wi = t - hi * 3;
    v8bf a0 = *(const v8bf*)&Dm[(hi * 16 + cn) * 72 + qd * 8];
    v8bf a1 = *(const v8bf*)&Dm[(hi * 16 + cn) * 72 + 32 + qd * 8];
    v8bf b0 = *(const v8bf*)&Tt[(wi * 16 + cn) * 72 + qd * 8];
    v8bf b1 = *(const v8bf*)&Tt[(wi * 16 + cn) * 72 + 32 + qd * 8];
    v4f acc = (v4f){0.f, 0.f, 0.f, 0.f};
    acc = MFMA_16x16x32_BF16(a0, b0, acc);
    acc = MFMA_16x16x32_BF16(a1, b1, acc);
    int w = wi * 16 + cn;                      // C/D: col=w, row=h
    if (!isV){
      #pragma unroll
      for (int r = 0; r < 4; r++){
        int l = (hi * 16 + qd * 4 + r) * 48 + w;
        KT[((size_t)b * L_TOT + l) * C_TOT + c] = (__bf16)((acc[r] + bias) * KSCALE);
      }
    } else {
      #pragma unroll
      for (int r = 0; r < 4; r++){
        int l = (hi * 16 + qd * 4 + r) * 48 + w;
        Vg[(size_t)img * 2304 + l] = (__bf16)(acc[r] + bias);
      }
    }
  }
}

// ================= MFMA flash attention, async-staged =================
__global__ __launch_bounds__(256) void k_attn(const __bf16* __restrict__ QT,
                                              const __bf16* __restrict__ KT,
                                              const __bf16* __restrict__ V,
                                              __bf16* __restrict__ AO){
  const int L = L_TOT;
  int bh = blockIdx.y;
  int b = bh >> 3, h = bh & 7;
  int c0 = h * 16;
  const __bf16* QTb = QT + (size_t)b * L * C_TOT;
  const __bf16* KTb = KT + (size_t)b * L * C_TOT;
  const __bf16* Vb  = V  + ((size_t)b * C_TOT + c0) * L;
  int tid = threadIdx.x;
  int wave = tid >> 6, lane = tid & 63;
  int qd = lane >> 4, cn = lane & 15;
  int l0 = blockIdx.x * 64;

  __shared__ __align__(16) __bf16 smem[8192 + 8192 + 2560];
  __bf16* Kt  = smem;
  __bf16* Vs  = smem + 8192;
  __bf16* Ptw = smem + 16384 + wave * 640;

  v8bf qf[4];
  #pragma unroll
  for (int t = 0; t < 4; t++){
    #pragma unroll
    for (int j = 0; j < 8; j++) qf[t][j] = (__bf16)0.0f;
  }
  if (qd < 2){
    #pragma unroll
    for (int t = 0; t < 4; t++)
      qf[t] = *(const v8bf*)&QTb[(size_t)(l0 + t * 16 + cn) * C_TOT + c0 + qd * 8];
  }

  v4f acc[4];
  float den[4] = {0.f, 0.f, 0.f, 0.f};
  #pragma unroll
  for (int t = 0; t < 4; t++) acc[t] = (v4f){0.f, 0.f, 0.f, 0.f};

  for (int ch = 0; ch < 5; ch++){
    int s0 = ch * 512;
    int cnt = (ch == 4) ? 256 : 512;
    __syncthreads();
    {
      int per = (cnt >> 5) >> 2;
      for (int jj = 0; jj < per; jj++){
        int j = wave * per + jj;
        int s = j * 32 + (lane >> 1);
        async_cp16(KTb + (size_t)(s0 + s) * C_TOT + c0 + (lane & 1) * 8,
                   Kt + j * 512);
      }
      if (cnt == 512){
        #pragma unroll
        for (int jj = 0; jj < 4; jj++){
          int d = wave * 4 + jj;
          async_cp16(Vb + (size_t)d * L + s0 + ((lane ^ (d & 7)) << 3),
                     Vs + d * 512);
        }
      } else {
        int d = tid >> 4, og = tid & 15;
        const __bf16* gp = Vb + (size_t)d * L + s0 + og * 16;
        v8bf v0 = *(const v8bf*)gp;
        v8bf v1 = *(const v8bf*)(gp + 8);
        int pd = d & 7;
        *(v8bf*)&Vs[d * 512 + (((og * 2)     ^ pd) << 3)] = v0;
        *(v8bf*)&Vs[d * 512 + (((og * 2 + 1) ^ pd) << 3)] = v1;
      }
    }
    __syncthreads();

    int nsu = cnt >> 7;
    int wbase = wave * (cnt >> 2);
    for (int su = 0; su < nsu; su++){
      int sb = wbase + su * 32;
      v8bf a0, a1;
      #pragma unroll
      for (int j = 0; j < 8; j++){ a0[j] = (__bf16)0.0f; a1[j] = (__bf16)0.0f; }
      if (qd < 2){
        a0 = *(const v8bf*)&Kt[(sb + cn) * 16 + qd * 8];
        a1 = *(const v8bf*)&Kt[(sb + 16 + cn) * 16 + qd * 8];
      }
      int jv = sb >> 3;
      v8bf vf = *(const v8bf*)&Vs[cn * 512 + (((jv + qd) ^ (cn & 7)) << 3)];
      #pragma unroll
      for (int t = 0; t < 4; t++){
        v4f z = {0.f, 0.f, 0.f, 0.f};
        v4f st0 = MFMA_16x16x32_BF16(a0, qf[t], z);
        v4f st1 = MFMA_16x16x32_BF16(a1, qf[t], z);
        float p0[4], p1[4];
        #pragma unroll
        for (int i = 0; i < 4; i++){
          p0[i] = EXP2(st0[i]); den[t] += p0[i];
          p1[i] = EXP2(st1[i]); den[t] += p1[i];
        }
        v4bf w0, w1;
        #pragma unroll
        for (int i = 0; i < 4; i++){ w0[i] = (__bf16)p0[i]; w1[i] = (__bf16)p1[i]; }
        *(v4bf*)&Ptw[cn * 40 + qd * 4]      = w0;
        *(v4bf*)&Ptw[cn * 40 + 16 + qd * 4] = w1;
        v8bf pf = *(const v8bf*)&Ptw[cn * 40 + qd * 8];
        acc[t] = MFMA_16x16x32_BF16(vf, pf, acc[t]);
      }
    }
  }

  __syncthreads();
  float* redA = (float*)smem;
  float* redD = (float*)(smem + 8192);
  #pragma unroll
  for (int t = 0; t < 4; t++){
    *(v4f*)&redA[((wave * 4 + t) * 64 + lane) * 4] = acc[t];
    redD[(wave * 4 + t) * 64 + lane] = den[t];
  }
  __syncthreads();
  {
    int t = wave;
    v4f a = (v4f){0.f, 0.f, 0.f, 0.f};
    float dn = 0.f;
    #pragma unroll
    for (int w2 = 0; w2 < 4; w2++){
      v4f xx = *(const v4f*)&redA[((w2 * 4 + t) * 64 + lane) * 4];
      a[0] += xx[0]; a[1] += xx[1]; a[2] += xx[2]; a[3] += xx[3];
      dn += redD[(w2 * 4 + t) * 64 + lane];
    }
    dn += __shfl_xor(dn, 16);
    dn += __shfl_xor(dn, 32);
    float inv = 1.0f / dn;
    __bf16* Ao = AO + ((size_t)b * C_TOT + c0) * L;
    #pragma unroll
    for (int r2 = 0; r2 < 4; r2++)
      Ao[(size_t)(qd * 4 + r2) * L + l0 + t * 16 + cn] = (__bf16)(a[r2] * inv);
  }
}

// ================= output projection (bf16 B, W split in regs) =================
__global__ __launch_bounds__(256) void k_oproj(const __bf16* __restrict__ AO,
                                               const float* __restrict__ Wo, const float* __restrict__ bo,
                                               float* __restrict__ out){
  __shared__ __align__(16) __bf16 Bs[32 * 136];
  int b = blockIdx.y, n0 = blockIdx.x * 32;
  int tid = threadIdx.x;
  const int wave = tid >> 6, lane = tid & 63, qd = lane >> 4, cn = lane & 15;
  const int m0 = wave * 32;
  v8bf ahi[2][4], alo[2][4];
  #pragma unroll
  for (int rt = 0; rt < 2; rt++)
    #pragma unroll
    for (int ks = 0; ks < 4; ks++){
      const float* wp = Wo + (size_t)(m0 + rt * 16 + cn) * C_TOT + ks * 32 + qd * 8;
      float4 w0 = *(const float4*)wp;
      float4 w1 = *(const float4*)(wp + 4);
      float wv[8] = {w0.x, w0.y, w0.z, w0.w, w1.x, w1.y, w1.z, w1.w};
      #pragma unroll
      for (int j = 0; j < 8; j++){
        __bf16 h = (__bf16)wv[j];
        ahi[rt][ks][j] = h;
        alo[rt][ks][j] = (__bf16)(wv[j] - (float)h);
      }
    }
  {
    int k = tid >> 1, nh = tid & 1;
    const __bf16* src = AO + ((size_t)b * C_TOT + k) * L_TOT + n0 + nh * 16;
    v8bf x0 = *(const v8bf*)src;
    v8bf x1 = *(const v8bf*)(src + 8);
    #pragma unroll
    for (int i = 0; i < 8; i++){
      Bs[(nh * 16 + i) * 136 + k] = x0[i];
      Bs[(nh * 16 + 8 + i) * 136 + k] = x1[i];
    }
  }
  __syncthreads();
  v4f acc[2][2];
  #pragma unroll
  for (int rt = 0; rt < 2; rt++)
    #pragma unroll
    for (int ct = 0; ct < 2; ct++) acc[rt][ct] = (v4f){0.f, 0.f, 0.f, 0.f};
  #pragma unroll
  for (int ks = 0; ks < 4; ks++){
    v8bf bf[2];
    #pragma unroll
    for (int ct = 0; ct < 2; ct++)
      bf[ct] = *(const v8bf*)&Bs[(ct * 16 + cn) * 136 + ks * 32 + qd * 8];
    #pragma unroll
    for (int rt = 0; rt < 2; rt++)
      #pragma unroll
      for (int ct = 0; ct < 2; ct++){
        acc[rt][ct] = MFMA_16x16x32_BF16(ahi[rt][ks], bf[ct], acc[rt][ct]);
        acc[rt][ct] = MFMA_16x16x32_BF16(alo[rt][ks], bf[ct], acc[rt][ct]);
      }
  }
  float* ob = out + (size_t)b * C_TOT * L_TOT;
  #pragma unroll
  for (int rt = 0; rt < 2; rt++){
    float bv[4];
    #pragma unroll
    for (int r = 0; r < 4; r++) bv[r] = bo[m0 + rt * 16 + qd * 4 + r];
    #pragma unroll
    for (int ct = 0; ct < 2; ct++){
      int col = n0 + ct * 16 + cn;
      #pragma unroll
      for (int r = 0; r < 4; r++)
        ob[(size_t)(m0 + rt * 16 + qd * 4 + r) * L_TOT + col] = acc[rt][ct][r] + bv[r];
    }
  }
}

extern "C" void kernel_launch(void* const* d_in, const int* in_sizes, int n_in,
                              void* d_out, int out_size, void* d_ws, size_t ws_size,
                              hipStream_t stream){
  const float* freq = (const float*)d_in[0];
  const float* spat = (const float*)d_in[1];
  const float* Wq = (const float*)d_in[2]; const float* bq = (const float*)d_in[3];
  const float* Wk = (const float*)d_in[4]; const float* bk = (const float*)d_in[5];
  const float* Wv = (const float*)d_in[6]; const float* bv = (const float*)d_in[7];
  const float* Wo = (const float*)d_in[8]; const float* bo = (const float*)d_in[9];
  __bf16* base = (__bf16*)d_ws;

  __bf16* QTg  = base;                 // [b][l][c]
  __bf16* Kraw = base + 589824;        // [b][c][l], pre-DCT, no bias
  __bf16* Vraw = base + 1179648;       // [b][c][l], pre-DCT, no bias
  __bf16* KTg  = base + 1769472;       // [b][l][c], DCT'd, +bk, *KSCALE
  __bf16* Vg   = base + 2359296;       // [b][c][l], DCT'd, +bv
  __bf16* AOg  = base + 2949120;       // [b][c][l]
  float* out = (float*)d_out;

  k_qkv<<<dim3(432), dim3(256), 0, stream>>>(freq, spat, Wq, bq, Wk, bk, Wv, bv,
                                             QTg, Kraw, Vraw);
  k_dct_kv<<<dim3(512), dim3(256), 0, stream>>>(Kraw, Vraw, bk, bv, KTg, Vg);
  k_attn<<<dim3(36, 16), dim3(256), 0, stream>>>(QTg, KTg, Vg, AOg);
  k_oproj<<<dim3(72, 2), dim3(256), 0, stream>>>(AOg, Wo, bo, out);
}

// Round 10
// 116.270 us; speedup vs baseline: 4.0787x; 1.0476x over previous
//
#include <hip/hip_runtime.h>
#include <math.h>

#define L_TOT 2304
#define C_TOT 128
// fold 1/ln2 into K so softmax uses native exp2
#define KSCALE 0.36067376022224085f   // 0.25 * log2(e)

#if __has_builtin(__builtin_amdgcn_exp2f)
#define EXP2(x) __builtin_amdgcn_exp2f(x)
#else
#define EXP2(x) __expf(0.69314718055994531f * (x))
#endif

typedef float v4f  __attribute__((ext_vector_type(4)));
typedef __bf16 v8bf __attribute__((ext_vector_type(8)));
typedef __bf16 v4bf __attribute__((ext_vector_type(4)));

#define MFMA_16x16x32_BF16(A, B, C) __builtin_amdgcn_mfma_f32_16x16x32_bf16((A), (B), (C), 0, 0, 0)

// async 16B/lane global->LDS: LDS dest is wave-uniform base + lane*16 (linear!)
__device__ __forceinline__ void async_cp16(const __bf16* g, __bf16* l){
  __builtin_amdgcn_global_load_lds((const __attribute__((address_space(1))) unsigned int*)g,
                                   (__attribute__((address_space(3))) unsigned int*)l,
                                   16, 0, 0);
}

// ================= split-precision MFMA projection =================
// One 128(M) x 32(N) tile of Y = W @ X + bscale*bias per block.
// W,X fp32 -> hi/lo bf16; Y = Whi*Xhi + Whi*Xlo + Wlo*Xhi (fp32-equiv).
// MODE 1: Yh[l][m] bf16 transposed, *scale ; 2: Yh[m][l] bf16
template<int MODE>
__device__ __forceinline__ void mfma_proj(const float* __restrict__ W,
                                          const float* __restrict__ bias,
                                          const float* __restrict__ Xb,
                                          __bf16* __restrict__ Yh,
                                          float scale, float bscale,
                                          int n0, __bf16* Bhi, int tid){
  __bf16* Blo = Bhi + 4352;            // [32][136] each, pad->bank-uniform
  const int wave = tid >> 6, lane = tid & 63, qd = lane >> 4, cn = lane & 15;
  const int m0 = wave * 32;
  v8bf ahi[2][4], alo[2][4];
  #pragma unroll
  for (int rt = 0; rt < 2; rt++)
    #pragma unroll
    for (int ks = 0; ks < 4; ks++){
      const float* wp = W + (size_t)(m0 + rt * 16 + cn) * C_TOT + ks * 32 + qd * 8;
      float4 w0 = *(const float4*)wp;
      float4 w1 = *(const float4*)(wp + 4);
      float wv[8] = {w0.x, w0.y, w0.z, w0.w, w1.x, w1.y, w1.z, w1.w};
      #pragma unroll
      for (int j = 0; j < 8; j++){
        __bf16 h = (__bf16)wv[j];
        ahi[rt][ks][j] = h;
        alo[rt][ks][j] = (__bf16)(wv[j] - (float)h);
      }
    }
  {
    int k = tid >> 1, nh = tid & 1;
    const float* xp = Xb + (size_t)k * L_TOT + n0 + nh * 16;
    float4 x0 = *(const float4*)xp;
    float4 x1 = *(const float4*)(xp + 4);
    float4 x2 = *(const float4*)(xp + 8);
    float4 x3 = *(const float4*)(xp + 12);
    float xv[16] = {x0.x, x0.y, x0.z, x0.w, x1.x, x1.y, x1.z, x1.w,
                    x2.x, x2.y, x2.z, x2.w, x3.x, x3.y, x3.z, x3.w};
    #pragma unroll
    for (int i = 0; i < 16; i++){
      __bf16 h = (__bf16)xv[i];
      int row = nh * 16 + i;
      Bhi[row * 136 + k] = h;
      Blo[row * 136 + k] = (__bf16)(xv[i] - (float)h);
    }
  }
  __syncthreads();
  v4f acc[2][2];
  #pragma unroll
  for (int rt = 0; rt < 2; rt++)
    #pragma unroll
    for (int ct = 0; ct < 2; ct++) acc[rt][ct] = (v4f){0.f, 0.f, 0.f, 0.f};
  #pragma unroll
  for (int ks = 0; ks < 4; ks++){
    v8bf bhi[2], blo[2];
    #pragma unroll
    for (int ct = 0; ct < 2; ct++){
      bhi[ct] = *(const v8bf*)&Bhi[(ct * 16 + cn) * 136 + ks * 32 + qd * 8];
      blo[ct] = *(const v8bf*)&Blo[(ct * 16 + cn) * 136 + ks * 32 + qd * 8];
    }
    #pragma unroll
    for (int rt = 0; rt < 2; rt++)
      #pragma unroll
      for (int ct = 0; ct < 2; ct++){
        acc[rt][ct] = MFMA_16x16x32_BF16(ahi[rt][ks], bhi[ct], acc[rt][ct]);
        acc[rt][ct] = MFMA_16x16x32_BF16(ahi[rt][ks], blo[ct], acc[rt][ct]);
        acc[rt][ct] = MFMA_16x16x32_BF16(alo[rt][ks], bhi[ct], acc[rt][ct]);
      }
  }
  #pragma unroll
  for (int rt = 0; rt < 2; rt++){
    float bv[4];
    #pragma unroll
    for (int r = 0; r < 4; r++) bv[r] = bias[m0 + rt * 16 + qd * 4 + r] * bscale;
    #pragma unroll
    for (int ct = 0; ct < 2; ct++){
      int col = n0 + ct * 16 + cn;
      if (MODE == 1){
        v4bf kk;
        #pragma unroll
        for (int r = 0; r < 4; r++) kk[r] = (__bf16)((acc[rt][ct][r] + bv[r]) * scale);
        *(v4bf*)&Yh[(size_t)col * C_TOT + m0 + rt * 16 + qd * 4] = kk;
      } else {
        #pragma unroll
        for (int r = 0; r < 4; r++)
          Yh[(size_t)(m0 + rt * 16 + qd * 4 + r) * L_TOT + col] = (__bf16)(acc[rt][ct][r] + bv[r]);
      }
    }
  }
}

// ================= stage 1: Q,K,V projections (no deps; DCT commuted past proj) =================
__global__ __launch_bounds__(256) void k_qkv(
    const float* __restrict__ freq, const float* __restrict__ spat,
    const float* __restrict__ Wq, const float* __restrict__ bq,
    const float* __restrict__ Wk, const float* __restrict__ bk,
    const float* __restrict__ Wv, const float* __restrict__ bv,
    __bf16* __restrict__ QT, __bf16* __restrict__ Kraw, __bf16* __restrict__ Vraw){
  __shared__ __align__(16) unsigned char smraw[17408];
  int job = blockIdx.x / 144;
  int idx = blockIdx.x % 144;
  int b = idx / 72, n0 = (idx % 72) * 32;
  size_t off = (size_t)b * C_TOT * L_TOT;
  if (job == 0)
    mfma_proj<1>(Wq, bq, freq + off, QT + (size_t)b * L_TOT * C_TOT, 1.0f, 1.0f, n0, (__bf16*)smraw, threadIdx.x);
  else if (job == 1)
    mfma_proj<2>(Wk, bk, spat + off, Kraw + off, 1.0f, 0.0f, n0, (__bf16*)smraw, threadIdx.x);
  else
    mfma_proj<2>(Wv, bv, spat + off, Vraw + off, 1.0f, 0.0f, n0, (__bf16*)smraw, threadIdx.x);
}

// ================= stage 2: MFMA 2D-DCT on Kraw/Vraw images =================
__global__ __launch_bounds__(256) void k_dct_kv(const __bf16* __restrict__ Kraw,
                                                const __bf16* __restrict__ Vraw,
                                                const float* __restrict__ bk,
                                                const float* __restrict__ bv,
                                                __bf16* __restrict__ KT,
                                                __bf16* __restrict__ Vg){
  __shared__ __align__(16) __bf16 Xs[3456];   // [48][72]
  __shared__ __align__(16) __bf16 Dm[3456];   // D[a][n], rows padded
  __shared__ __align__(16) __bf16 Tt[3456];   // T^T[w][m]
  int blk = blockIdx.x, tid = threadIdx.x;
  int isV = blk >> 8;
  int img = blk & 255;
  int b = img >> 7, c = img & 127;
  const __bf16* src = (isV ? Vraw : Kraw) + (size_t)img * 2304;
  float bias = (isV ? bv : bk)[c];
  for (int i = tid; i < 1728; i += 256){
    ((unsigned int*)Xs)[i] = 0u;
    ((unsigned int*)Dm)[i] = 0u;
    ((unsigned int*)Tt)[i] = 0u;
  }
  __syncthreads();
  for (int i = tid; i < 2304; i += 256){
    int a = i / 48, n = i - a * 48;
    int m = ((2 * n + 1) * a) % 192;      // exact angle reduction, cos period = 192
    float v = cosf(0.032724923474893679f * (float)m) * 0.204124145231931508f;
    if (a == 0) v *= 0.707106781186547524f;
    Dm[a * 72 + n] = (__bf16)v;
  }
  for (int t = tid; t < 288; t += 256){    // rows are 6 v8bf each (48 = 6*8)
    int m = t / 6, j = t - m * 6;
    *(v8bf*)&Xs[m * 72 + j * 8] = *(const v8bf*)(src + t * 8);
  }
  __syncthreads();
  int wave = tid >> 6, lane = tid & 63, qd = lane >> 4, cn = lane & 15;
  // pass 1: T[m][w] = sum_n X[m][n] D[w][n]
  for (int t = wave; t < 9; t += 4){
    int mi = t / 3, wi = t - mi * 3;
    v8bf a0 = *(const v8bf*)&Xs[(mi * 16 + cn) * 72 + qd * 8];
    v8bf a1 = *(const v8bf*)&Xs[(mi * 16 + cn) * 72 + 32 + qd * 8];
    v8bf b0 = *(const v8bf*)&Dm[(wi * 16 + cn) * 72 + qd * 8];
    v8bf b1 = *(const v8bf*)&Dm[(wi * 16 + cn) * 72 + 32 + qd * 8];
    v4f acc = (v4f){0.f, 0.f, 0.f, 0.f};
    acc = MFMA_16x16x32_BF16(a0, b0, acc);
    acc = MFMA_16x16x32_BF16(a1, b1, acc);
    v4bf w4;
    #pragma unroll
    for (int r = 0; r < 4; r++) w4[r] = (__bf16)acc[r];
    *(v4bf*)&Tt[(wi * 16 + cn) * 72 + mi * 16 + qd * 4] = w4;   // col=w, rows m
  }
  __syncthreads();
  // pass 2: F[h][w] = sum_m D[h][m] T[m][w]
  for (int t = wave; t < 9; t += 4){
    int hi = t / 3, wi = t - hi * 3;
    v8bf a0 = *(const v8bf*)&Dm[(hi * 16 + cn) * 72 + qd * 8];
    v8bf a1 = *(const v8bf*)&Dm[(hi * 16 + cn) * 72 + 32 + qd * 8];
    v8bf b0 = *(const v8bf*)&Tt[(wi * 16 + cn) * 72 + qd * 8];
    v8bf b1 = *(const v8bf*)&Tt[(wi * 16 + cn) * 72 + 32 + qd * 8];
    v4f acc = (v4f){0.f, 0.f, 0.f, 0.f};
    acc = MFMA_16x16x32_BF16(a0, b0, acc);
    acc = MFMA_16x16x32_BF16(a1, b1, acc);
    int w = wi * 16 + cn;                      // C/D: col=w, row=h
    if (!isV){
      #pragma unroll
      for (int r = 0; r < 4; r++){
        int l = (hi * 16 + qd * 4 + r) * 48 + w;
        KT[((size_t)b * L_TOT + l) * C_TOT + c] = (__bf16)((acc[r] + bias) * KSCALE);
      }
    } else {
      #pragma unroll
      for (int r = 0; r < 4; r++){
        int l = (hi * 16 + qd * 4 + r) * 48 + w;
        Vg[(size_t)img * 2304 + l] = (__bf16)(acc[r] + bias);
      }
    }
  }
}

// ================= MFMA flash attention, async-staged, 48-l blocks =================
// Grid 48x16 = 768 blocks = exactly 3/CU (LDS 48.1KB caps at 3) -> perfectly
// balanced single round; trans pipe (exp2) saturated at 3 waves/SIMD.
__global__ __launch_bounds__(256) void k_attn(const __bf16* __restrict__ QT,
                                              const __bf16* __restrict__ KT,
                                              const __bf16* __restrict__ V,
                                              __bf16* __restrict__ AO){
  const int L = L_TOT;
  int bh = blockIdx.y;
  int b = bh >> 3, h = bh & 7;
  int c0 = h * 16;
  const __bf16* QTb = QT + (size_t)b * L * C_TOT;
  const __bf16* KTb = KT + (size_t)b * L * C_TOT;
  const __bf16* Vb  = V  + ((size_t)b * C_TOT + c0) * L;
  int tid = threadIdx.x;
  int wave = tid >> 6, lane = tid & 63;
  int qd = lane >> 4, cn = lane & 15;
  int l0 = blockIdx.x * 48;

  // Kt[512][16] 16KB | Vs[16][512] 16KB | Pt[4 waves][3 tiles][640] 15KB = 48128 B
  __shared__ __align__(16) __bf16 smem[8192 + 8192 + 7680];
  __bf16* Kt = smem;
  __bf16* Vs = smem + 8192;
  __bf16* Pt = smem + 16384;

  v8bf qf[3];
  #pragma unroll
  for (int t = 0; t < 3; t++){
    #pragma unroll
    for (int j = 0; j < 8; j++) qf[t][j] = (__bf16)0.0f;
  }
  if (qd < 2){
    #pragma unroll
    for (int t = 0; t < 3; t++)
      qf[t] = *(const v8bf*)&QTb[(size_t)(l0 + t * 16 + cn) * C_TOT + c0 + qd * 8];
  }

  v4f acc[3];
  float den[3] = {0.f, 0.f, 0.f};
  #pragma unroll
  for (int t = 0; t < 3; t++) acc[t] = (v4f){0.f, 0.f, 0.f, 0.f};

  for (int ch = 0; ch < 5; ch++){
    int s0 = ch * 512;
    int cnt = (ch == 4) ? 256 : 512;
    __syncthreads();
    {
      int per = (cnt >> 5) >> 2;
      for (int jj = 0; jj < per; jj++){
        int j = wave * per + jj;
        int s = j * 32 + (lane >> 1);
        async_cp16(KTb + (size_t)(s0 + s) * C_TOT + c0 + (lane & 1) * 8,
                   Kt + j * 512);
      }
      if (cnt == 512){
        #pragma unroll
        for (int jj = 0; jj < 4; jj++){
          int d = wave * 4 + jj;
          async_cp16(Vb + (size_t)d * L + s0 + ((lane ^ (d & 7)) << 3),
                     Vs + d * 512);
        }
      } else {
        int d = tid >> 4, og = tid & 15;
        const __bf16* gp = Vb + (size_t)d * L + s0 + og * 16;
        v8bf v0 = *(const v8bf*)gp;
        v8bf v1 = *(const v8bf*)(gp + 8);
        int pd = d & 7;
        *(v8bf*)&Vs[d * 512 + (((og * 2)     ^ pd) << 3)] = v0;
        *(v8bf*)&Vs[d * 512 + (((og * 2 + 1) ^ pd) << 3)] = v1;
      }
    }
    __syncthreads();

    int nsu = cnt >> 7;
    int wbase = wave * (cnt >> 2);
    for (int su = 0; su < nsu; su++){
      int sb = wbase + su * 32;
      v8bf a0, a1;
      #pragma unroll
      for (int j = 0; j < 8; j++){ a0[j] = (__bf16)0.0f; a1[j] = (__bf16)0.0f; }
      if (qd < 2){
        a0 = *(const v8bf*)&Kt[(sb + cn) * 16 + qd * 8];
        a1 = *(const v8bf*)&Kt[(sb + 16 + cn) * 16 + qd * 8];
      }
      int jv = sb >> 3;
      v8bf vf = *(const v8bf*)&Vs[cn * 512 + (((jv + qd) ^ (cn & 7)) << 3)];
      #pragma unroll
      for (int t = 0; t < 3; t++){
        v4f z = {0.f, 0.f, 0.f, 0.f};
        v4f st0 = MFMA_16x16x32_BF16(a0, qf[t], z);
        v4f st1 = MFMA_16x16x32_BF16(a1, qf[t], z);
        float p0[4], p1[4];
        #pragma unroll
        for (int i = 0; i < 4; i++){
          p0[i] = EXP2(st0[i]); den[t] += p0[i];
          p1[i] = EXP2(st1[i]); den[t] += p1[i];
        }
        v4bf w0, w1;
        #pragma unroll
        for (int i = 0; i < 4; i++){ w0[i] = (__bf16)p0[i]; w1[i] = (__bf16)p1[i]; }
        __bf16* Ptw = Pt + (wave * 3 + t) * 640;
        *(v4bf*)&Ptw[cn * 40 + qd * 4]      = w0;
        *(v4bf*)&Ptw[cn * 40 + 16 + qd * 4] = w1;
        v8bf pf = *(const v8bf*)&Ptw[cn * 40 + qd * 8];
        acc[t] = MFMA_16x16x32_BF16(vf, pf, acc[t]);
      }
    }
  }

  // cross-wave combine: 12 (wave,tile) slots, 15360 B total in smem
  __syncthreads();
  float* redA = (float*)smem;            // 3072 floats
  float* redD = (float*)smem + 3072;     // 768 floats
  #pragma unroll
  for (int t = 0; t < 3; t++){
    *(v4f*)&redA[((wave * 3 + t) * 64 + lane) * 4] = acc[t];
    redD[(wave * 3 + t) * 64 + lane] = den[t];
  }
  __syncthreads();
  if (wave < 3){
    int t = wave;
    v4f a = (v4f){0.f, 0.f, 0.f, 0.f};
    float dn = 0.f;
    #pragma unroll
    for (int w2 = 0; w2 < 4; w2++){
      v4f xx = *(const v4f*)&redA[((w2 * 3 + t) * 64 + lane) * 4];
      a[0] += xx[0]; a[1] += xx[1]; a[2] += xx[2]; a[3] += xx[3];
      dn += redD[(w2 * 3 + t) * 64 + lane];
    }
    dn += __shfl_xor(dn, 16);
    dn += __shfl_xor(dn, 32);
    float inv = 1.0f / dn;
    __bf16* Ao = AO + ((size_t)b * C_TOT + c0) * L;
    #pragma unroll
    for (int r2 = 0; r2 < 4; r2++)
      Ao[(size_t)(qd * 4 + r2) * L + l0 + t * 16 + cn] = (__bf16)(a[r2] * inv);
  }
}

// ================= output projection (bf16 B, W split in regs) =================
__global__ __launch_bounds__(256) void k_oproj(const __bf16* __restrict__ AO,
                                               const float* __restrict__ Wo, const float* __restrict__ bo,
                                               float* __restrict__ out){
  __shared__ __align__(16) __bf16 Bs[32 * 136];
  int b = blockIdx.y, n0 = blockIdx.x * 32;
  int tid = threadIdx.x;
  const int wave = tid >> 6, lane = tid & 63, qd = lane >> 4, cn = lane & 15;
  const int m0 = wave * 32;
  v8bf ahi[2][4], alo[2][4];
  #pragma unroll
  for (int rt = 0; rt < 2; rt++)
    #pragma unroll
    for (int ks = 0; ks < 4; ks++){
      const float* wp = Wo + (size_t)(m0 + rt * 16 + cn) * C_TOT + ks * 32 + qd * 8;
      float4 w0 = *(const float4*)wp;
      float4 w1 = *(const float4*)(wp + 4);
      float wv[8] = {w0.x, w0.y, w0.z, w0.w, w1.x, w1.y, w1.z, w1.w};
      #pragma unroll
      for (int j = 0; j < 8; j++){
        __bf16 h = (__bf16)wv[j];
        ahi[rt][ks][j] = h;
        alo[rt][ks][j] = (__bf16)(wv[j] - (float)h);
      }
    }
  {
    int k = tid >> 1, nh = tid & 1;
    const __bf16* src = AO + ((size_t)b * C_TOT + k) * L_TOT + n0 + nh * 16;
    v8bf x0 = *(const v8bf*)src;
    v8bf x1 = *(const v8bf*)(src + 8);
    #pragma unroll
    for (int i = 0; i < 8; i++){
      Bs[(nh * 16 + i) * 136 + k] = x0[i];
      Bs[(nh * 16 + 8 + i) * 136 + k] = x1[i];
    }
  }
  __syncthreads();
  v4f acc[2][2];
  #pragma unroll
  for (int rt = 0; rt < 2; rt++)
    #pragma unroll
    for (int ct = 0; ct < 2; ct++) acc[rt][ct] = (v4f){0.f, 0.f, 0.f, 0.f};
  #pragma unroll
  for (int ks = 0; ks < 4; ks++){
    v8bf bf[2];
    #pragma unroll
    for (int ct = 0; ct < 2; ct++)
      bf[ct] = *(const v8bf*)&Bs[(ct * 16 + cn) * 136 + ks * 32 + qd * 8];
    #pragma unroll
    for (int rt = 0; rt < 2; rt++)
      #pragma unroll
      for (int ct = 0; ct < 2; ct++){
        acc[rt][ct] = MFMA_16x16x32_BF16(ahi[rt][ks], bf[ct], acc[rt][ct]);
        acc[rt][ct] = MFMA_16x16x32_BF16(alo[rt][ks], bf[ct], acc[rt][ct]);
      }
  }
  float* ob = out + (size_t)b * C_TOT * L_TOT;
  #pragma unroll
  for (int rt = 0; rt < 2; rt++){
    float bv[4];
    #pragma unroll
    for (int r = 0; r < 4; r++) bv[r] = bo[m0 + rt * 16 + qd * 4 + r];
    #pragma unroll
    for (int ct = 0; ct < 2; ct++){
      int col = n0 + ct * 16 + cn;
      #pragma unroll
      for (int r = 0; r < 4; r++)
        ob[(size_t)(m0 + rt * 16 + qd * 4 + r) * L_TOT + col] = acc[rt][ct][r] + bv[r];
    }
  }
}

extern "C" void kernel_launch(void* const* d_in, const int* in_sizes, int n_in,
                              void* d_out, int out_size, void* d_ws, size_t ws_size,
                              hipStream_t stream){
  const float* freq = (const float*)d_in[0];
  const float* spat = (const float*)d_in[1];
  const float* Wq = (const float*)d_in[2]; const float* bq = (const float*)d_in[3];
  const float* Wk = (const float*)d_in[4]; const float* bk = (const float*)d_in[5];
  const float* Wv = (const float*)d_in[6]; const float* bv = (const float*)d_in[7];
  const float* Wo = (const float*)d_in[8]; const float* bo = (const float*)d_in[9];
  __bf16* base = (__bf16*)d_ws;

  __bf16* QTg  = base;                 // [b][l][c]
  __bf16* Kraw = base + 589824;        // [b][c][l], pre-DCT, no bias
  __bf16* Vraw = base + 1179648;       // [b][c][l], pre-DCT, no bias
  __bf16* KTg  = base + 1769472;       // [b][l][c], DCT'd, +bk, *KSCALE
  __bf16* Vg   = base + 2359296;       // [b][c][l], DCT'd, +bv
  __bf16* AOg  = base + 2949120;       // [b][c][l]
  float* out = (float*)d_out;

  k_qkv<<<dim3(432), dim3(256), 0, stream>>>(freq, spat, Wq, bq, Wk, bk, Wv, bv,
                                             QTg, Kraw, Vraw);
  k_dct_kv<<<dim3(512), dim3(256), 0, stream>>>(Kraw, Vraw, bk, bv, KTg, Vg);
  k_attn<<<dim3(48, 16), dim3(256), 0, stream>>>(QTg, KTg, Vg, AOg);
  k_oproj<<<dim3(72, 2), dim3(256), 0, stream>>>(AOg, Wo, bo, out);
}